// Round 1
// baseline (16219.290 us; speedup 1.0000x reference)
//
#include <hip/hip_runtime.h>
#include <math.h>

#define PN 20000
#define DN 20000
#define SEQK 1024
#define EPPI 640000
#define EDDI 640000
#define EDTI 400000
#define NPAIRN 100000

typedef float4 f4;

__device__ __forceinline__ f4 ld4(const float* p) { return *reinterpret_cast<const f4*>(p); }
__device__ __forceinline__ void st4(float* p, f4 v) { *reinterpret_cast<f4*>(p) = v; }
__device__ __forceinline__ void acc4(f4& a, f4 b) { a.x+=b.x; a.y+=b.y; a.z+=b.z; a.w+=b.w; }
__device__ __forceinline__ void acc4s(f4& a, f4 b, float s) { a.x+=s*b.x; a.y+=s*b.y; a.z+=s*b.z; a.w+=s*b.w; }

// LayerNorm over a 256-wide row held as one float4 per lane across a 64-lane wave.
__device__ __forceinline__ void wave_ln(f4& x) {
  float s  = x.x + x.y + x.z + x.w;
  float ss = x.x*x.x + x.y*x.y + x.z*x.z + x.w*x.w;
#pragma unroll
  for (int o = 32; o; o >>= 1) { s += __shfl_xor(s, o, 64); ss += __shfl_xor(ss, o, 64); }
  float m = s * (1.f/256.f);
  float v = ss * (1.f/256.f) - m*m;
  float r = rsqrtf(v + 1e-5f);
  x.x = (x.x-m)*r; x.y = (x.y-m)*r; x.z = (x.z-m)*r; x.w = (x.w-m)*r;
}

// ---------------- GEMM: out[N,256] = X[N,K] @ Wt[256,K]^T (+bias)(+act) ----------------
// act: 0 none, 1 relu, 2 elu
__global__ __launch_bounds__(256) void gemm_nt(
    const float* __restrict__ X, const float* __restrict__ Wt,
    const float* __restrict__ bias, float* __restrict__ out,
    int N, int K, int act)
{
  __shared__ float Xs[64][17];
  __shared__ float Ws[64][17];
  const int tid = threadIdx.x;
  const int r0 = blockIdx.x * 64;
  const int c0 = blockIdx.y * 64;
  const int tx = tid & 15, ty = tid >> 4;
  const int lr = tid >> 2;          // load row 0..63
  const int lk = (tid & 3) * 4;     // load k-chunk 0,4,8,12
  float acc[4][4] = {};
  for (int k0 = 0; k0 < K; k0 += 16) {
    int xr = r0 + lr;
    f4 xv = make_float4(0.f,0.f,0.f,0.f);
    if (xr < N) xv = ld4(X + (size_t)xr * K + k0 + lk);
    Xs[lr][lk+0]=xv.x; Xs[lr][lk+1]=xv.y; Xs[lr][lk+2]=xv.z; Xs[lr][lk+3]=xv.w;
    f4 wv = ld4(Wt + (size_t)(c0 + lr) * K + k0 + lk);
    Ws[lr][lk+0]=wv.x; Ws[lr][lk+1]=wv.y; Ws[lr][lk+2]=wv.z; Ws[lr][lk+3]=wv.w;
    __syncthreads();
#pragma unroll
    for (int k = 0; k < 16; ++k) {
      float xr4[4], wc4[4];
#pragma unroll
      for (int i = 0; i < 4; ++i) xr4[i] = Xs[ty*4+i][k];
#pragma unroll
      for (int j = 0; j < 4; ++j) wc4[j] = Ws[tx*4+j][k];
#pragma unroll
      for (int i = 0; i < 4; ++i)
#pragma unroll
        for (int j = 0; j < 4; ++j) acc[i][j] += xr4[i]*wc4[j];
    }
    __syncthreads();
  }
#pragma unroll
  for (int i = 0; i < 4; ++i) {
    int r = r0 + ty*4 + i;
    if (r >= N) continue;
    f4 o;
    float* po = &o.x;
#pragma unroll
    for (int j = 0; j < 4; ++j) {
      int c = c0 + tx*4 + j;
      float v = acc[i][j];
      if (bias) v += bias[c];
      if (act == 1) v = fmaxf(v, 0.f);
      else if (act == 2) v = v > 0.f ? v : (expf(v) - 1.f);
      po[j] = v;
    }
    st4(out + (size_t)r * 256 + c0 + tx*4, o);
  }
}

// ---------------- degree / count ----------------
__global__ __launch_bounds__(256) void count_kernel(const int* __restrict__ idx, int* __restrict__ cnt, int n) {
  int i = blockIdx.x * 256 + threadIdx.x;
  if (i < n) atomicAdd(&cnt[idx[i]], 1);
}

__global__ __launch_bounds__(256) void finalize_deg(
    const int* __restrict__ degP, const int* __restrict__ degD,
    const int* __restrict__ cntD, const int* __restrict__ cntP,
    float* __restrict__ dinvP, float* __restrict__ dinvD,
    float* __restrict__ icD, float* __restrict__ icP, int n)
{
  int i = blockIdx.x * 256 + threadIdx.x;
  if (i < n) {
    dinvP[i] = rsqrtf((float)degP[i] + 1.f);  // +1 = self loop
    dinvD[i] = rsqrtf((float)degD[i] + 1.f);
    icD[i] = 1.f / fmaxf((float)cntD[i], 1.f);
    icP[i] = 1.f / fmaxf((float)cntP[i], 1.f);
  }
}

// ---------------- GCN edge scatter: A[dst] += dinv[src]*dinv[dst] * T[src] ----------------
__global__ __launch_bounds__(256) void scatter_gcn(
    const int* __restrict__ src, const int* __restrict__ dst,
    const float* __restrict__ dinv, const float* __restrict__ T,
    float* __restrict__ A, int nE)
{
  int e = (blockIdx.x * 256 + threadIdx.x) >> 6;
  if (e >= nE) return;
  int lane = threadIdx.x & 63;
  int s = src[e], d = dst[e];
  float nrm = dinv[s] * dinv[d];
  f4 t = ld4(T + (size_t)s * 256 + lane*4);
  float* a = A + (size_t)d * 256 + lane*4;
  atomicAdd(a+0, nrm*t.x);
  atomicAdd(a+1, nrm*t.y);
  atomicAdd(a+2, nrm*t.z);
  atomicAdd(a+3, nrm*t.w);
}

// ---------------- scatter-sum for scatter_mean: S[dst] += proj[src] ----------------
__global__ __launch_bounds__(256) void scatter_sum(
    const int* __restrict__ src, const int* __restrict__ dst,
    const float* __restrict__ proj, float* __restrict__ S, int nE)
{
  int e = (blockIdx.x * 256 + threadIdx.x) >> 6;
  if (e >= nE) return;
  int lane = threadIdx.x & 63;
  int s = src[e], d = dst[e];
  f4 t = ld4(proj + (size_t)s * 256 + lane*4);
  float* a = S + (size_t)d * 256 + lane*4;
  atomicAdd(a+0, t.x);
  atomicAdd(a+1, t.y);
  atomicAdd(a+2, t.z);
  atomicAdd(a+3, t.w);
}

// ---------------- combine: out = act( LN( A + dinv^2*T + gb + L + ic*S ) [*lw+lb] ) ----------------
__global__ __launch_bounds__(256) void combine_ln(
    const float* __restrict__ A, const float* __restrict__ T, const float* __restrict__ dinv,
    const float* __restrict__ gb, const float* __restrict__ L,
    const float* __restrict__ S, const float* __restrict__ ic,
    const float* __restrict__ lw, const float* __restrict__ lb,
    float* __restrict__ out, int n, int act)
{
  int row = (blockIdx.x * blockDim.x + threadIdx.x) >> 6;
  if (row >= n) return;
  int lane = threadIdx.x & 63;
  size_t base = (size_t)row * 256 + lane*4;
  f4 x = make_float4(0.f,0.f,0.f,0.f);
  if (A) acc4(x, ld4(A + base));
  if (T) { float dv = dinv[row]; acc4s(x, ld4(T + base), dv*dv); }
  if (gb) acc4(x, ld4(gb + lane*4));
  if (L) acc4(x, ld4(L + base));
  if (S) acc4s(x, ld4(S + base), ic[row]);
  wave_ln(x);
  if (lw) {
    f4 w = ld4(lw + lane*4), b = ld4(lb + lane*4);
    x.x = x.x*w.x + b.x; x.y = x.y*w.y + b.y; x.z = x.z*w.z + b.z; x.w = x.w*w.w + b.w;
  }
  if (act == 1) {
    x.x = fmaxf(x.x, 0.f); x.y = fmaxf(x.y, 0.f); x.z = fmaxf(x.z, 0.f); x.w = fmaxf(x.w, 0.f);
  } else if (act == 2) {
    x.x = x.x > 0.f ? x.x : expf(x.x)-1.f;
    x.y = x.y > 0.f ? x.y : expf(x.y)-1.f;
    x.z = x.z > 0.f ? x.z : expf(x.z)-1.f;
    x.w = x.w > 0.f ? x.w : expf(x.w)-1.f;
  }
  st4(out + base, x);
}

// ---------------- pair epilogue: complex fuse, one wave per pair ----------------
__global__ __launch_bounds__(256) void pair_kernel(
    const float* __restrict__ x1, const float* __restrict__ xfp,
    const float* __restrict__ p2, const float* __restrict__ xskip,
    const int* __restrict__ idx1, const int* __restrict__ idx2,
    const float* __restrict__ wR, const float* __restrict__ wI,
    float* __restrict__ out, int npair)
{
  int wid = (blockIdx.x * blockDim.x + threadIdx.x) >> 6;
  if (wid >= npair) return;
  int lane = threadIdx.x & 63;
  int f = lane * 4;
  size_t o1 = (size_t)idx1[wid] * 256 + f;
  size_t o2 = (size_t)idx2[wid] * 256 + f;

  f4 R1 = ld4(x1 + o1);    acc4(R1, ld4(xfp + o2));   wave_ln(R1);
  f4 I1 = ld4(p2 + o1);    acc4(I1, ld4(xskip + o2)); wave_ln(I1);
  f4 R2 = ld4(xskip + o1); acc4(R2, ld4(p2 + o2));    wave_ln(R2);
  f4 I2 = ld4(xfp + o1);   acc4(I2, ld4(x1 + o2));    wave_ln(I2);

  f4 R, I;
  R.x = R1.x*R2.x - I1.x*I2.x;  I.x = R1.x*I2.x + I1.x*R2.x;
  R.y = R1.y*R2.y - I1.y*I2.y;  I.y = R1.y*I2.y + I1.y*R2.y;
  R.z = R1.z*R2.z - I1.z*I2.z;  I.z = R1.z*I2.z + I1.z*R2.z;
  R.w = R1.w*R2.w - I1.w*I2.w;  I.w = R1.w*I2.w + I1.w*R2.w;
  wave_ln(R); wave_ln(I);

  f4 wr = ld4(wR + f), wi = ld4(wI + f);
  float r_ = R.x*wr.x + I.x*wi.x + R.y*wr.y + I.y*wi.y
           + R.z*wr.z + I.z*wi.z + R.w*wr.w + I.w*wi.w;
  float i_ = I.x*wr.x - R.x*wi.x + I.y*wr.y - R.y*wi.y
           + I.z*wr.z - R.z*wi.z + I.w*wr.w - R.w*wi.w;
  float t = r_ + i_;
#pragma unroll
  for (int o = 32; o; o >>= 1) t += __shfl_xor(t, o, 64);
  if (lane == 0) out[wid] = 1.f / (1.f + expf(-t));
}

extern "C" void kernel_launch(void* const* d_in, const int* in_sizes, int n_in,
                              void* d_out, int out_size, void* d_ws, size_t ws_size,
                              hipStream_t stream) {
  (void)in_sizes; (void)n_in; (void)out_size; (void)ws_size;
  const float* seq        = (const float*)d_in[0];
  const int*   ppi        = (const int*)d_in[1];
  const int*   ddi        = (const int*)d_in[2];
  const int*   dti        = (const int*)d_in[3];
  const int*   idx1       = (const int*)d_in[4];
  const int*   idx2       = (const int*)d_in[5];
  const float* seq_init_W = (const float*)d_in[6];
  const float* gs1_gcn_W  = (const float*)d_in[7];
  const float* gs1_gcn_b  = (const float*)d_in[8];
  const float* gs1_lin_W  = (const float*)d_in[9];
  const float* gs1_ln_w   = (const float*)d_in[10];
  const float* gs1_ln_b   = (const float*)d_in[11];
  const float* gs2_gcn_W  = (const float*)d_in[12];
  const float* gs2_gcn_b  = (const float*)d_in[13];
  const float* gs2_lin_W  = (const float*)d_in[14];
  const float* gs2_ln_w   = (const float*)d_in[15];
  const float* gs2_ln_b   = (const float*)d_in[16];
  const float* drug_emb   = (const float*)d_in[17];
  const float* prot_emb   = (const float*)d_in[18];
  const float* pp1_W = (const float*)d_in[19]; const float* pp1_b = (const float*)d_in[20];
  const float* td1_W = (const float*)d_in[21]; const float* td1_b = (const float*)d_in[22];
  const float* pr1_W = (const float*)d_in[23]; const float* pr1_b = (const float*)d_in[24];
  const float* dd1_W = (const float*)d_in[25]; const float* dd1_b = (const float*)d_in[26];
  const float* dt1_W = (const float*)d_in[27]; const float* dt1_b = (const float*)d_in[28];
  const float* dr1_W = (const float*)d_in[29]; const float* dr1_b = (const float*)d_in[30];
  const float* pp2_W = (const float*)d_in[31]; const float* pp2_b = (const float*)d_in[32];
  const float* td2_W = (const float*)d_in[33]; const float* td2_b = (const float*)d_in[34];
  const float* pr2_W = (const float*)d_in[35]; const float* pr2_b = (const float*)d_in[36];
  // d_in[37..42]: dd2/dt2/dr2 — dead code in ASC path
  const float* seq_fc_W  = (const float*)d_in[43];
  const float* skip_fc_W = (const float*)d_in[44];
  const float* wR = (const float*)d_in[45];
  const float* wI = (const float*)d_in[46];
  float* outp = (float*)d_out;

  float* ws = (float*)d_ws;
  const size_t NB = (size_t)PN * 256;
  float* W0 = ws + 0*NB;  // x_seq
  float* W1 = ws + 1*NB;
  float* W2 = ws + 2*NB;
  float* W3 = ws + 3*NB;
  float* W4 = ws + 4*NB;
  float* W5 = ws + 5*NB;
  float* W6 = ws + 6*NB;
  int*   degP = (int*)(ws + 7*NB);
  int*   degD = degP + PN;
  int*   cntD = degD + DN;
  int*   cntP = cntD + DN;
  float* dinvP = (float*)(cntP + PN);
  float* dinvD = dinvP + PN;
  float* icD   = dinvD + DN;
  float* icP   = icD + DN;

  const dim3 blk(256);
  const dim3 ggrid(313, 4);             // ceil(20000/64) x 256/64
  const dim3 rgrid((PN + 3) / 4);       // combine: 4 rows/block
  const dim3 egridP((EPPI + 3) / 4);    // scatter: 4 edges/block
  const dim3 egridD((EDDI + 3) / 4);
  const dim3 egridT((EDTI + 3) / 4);

  auto GEMM = [&](const float* X, const float* Wt, const float* bias, float* o, int K, int act) {
    hipLaunchKernelGGL(gemm_nt, ggrid, blk, 0, stream, X, Wt, bias, o, PN, K, act);
  };
  auto COMB = [&](const float* A, const float* T, const float* dv, const float* gb,
                  const float* L, const float* S, const float* ic,
                  const float* lw, const float* lb, float* o, int n, int act) {
    hipLaunchKernelGGL(combine_ln, rgrid, blk, 0, stream, A, T, dv, gb, L, S, ic, lw, lb, o, n, act);
  };

  // ---- degrees & counts (deterministic per call) ----
  hipMemsetAsync(degP, 0, 4 * sizeof(int) * PN, stream);
  hipLaunchKernelGGL(count_kernel, dim3((EPPI+255)/256), blk, 0, stream, ppi + EPPI, degP, EPPI);
  hipLaunchKernelGGL(count_kernel, dim3((EDDI+255)/256), blk, 0, stream, ddi + EDDI, degD, EDDI);
  hipLaunchKernelGGL(count_kernel, dim3((EDTI+255)/256), blk, 0, stream, dti,        cntD, EDTI);
  hipLaunchKernelGGL(count_kernel, dim3((EDTI+255)/256), blk, 0, stream, dti + EDTI, cntP, EDTI);
  hipLaunchKernelGGL(finalize_deg, dim3((PN+255)/256), blk, 0, stream,
                     degP, degD, cntD, cntP, dinvP, dinvD, icD, icP, PN);

  // ---- P1: x_seq = relu(seq @ seq_init_W^T) -> W0 ----
  GEMM(seq, seq_init_W, nullptr, W0, SEQK, 1);

  // ---- P2 (gs1): h -> W1 ----
  GEMM(W0, gs1_gcn_W, nullptr, W1, 256, 0);                       // t
  hipMemsetAsync(W2, 0, NB * 4, stream);
  hipLaunchKernelGGL(scatter_gcn, egridP, blk, 0, stream, ppi, ppi + EPPI, dinvP, W1, W2, EPPI);
  GEMM(W0, gs1_lin_W, nullptr, W3, 256, 0);                       // lin
  COMB(W2, W1, dinvP, gs1_gcn_b, W3, nullptr, nullptr, gs1_ln_w, gs1_ln_b, W1, PN, 1);

  // ---- P3 (gs2): x1 -> W2 ----
  GEMM(W1, gs2_gcn_W, nullptr, W2, 256, 0);
  hipMemsetAsync(W3, 0, NB * 4, stream);
  hipLaunchKernelGGL(scatter_gcn, egridP, blk, 0, stream, ppi, ppi + EPPI, dinvP, W2, W3, EPPI);
  GEMM(W1, gs2_lin_W, nullptr, W4, 256, 0);
  COMB(W3, W2, dinvP, gs2_gcn_b, W4, nullptr, nullptr, gs2_ln_w, gs2_ln_b, W2, PN, 0);

  // ---- P4d (drug layer 1): d -> W1 ----
  GEMM(drug_emb, dd1_W, nullptr, W1, 256, 0);
  hipMemsetAsync(W3, 0, NB * 4, stream);
  hipLaunchKernelGGL(scatter_gcn, egridD, blk, 0, stream, ddi, ddi + EDDI, dinvD, W1, W3, EDDI);
  GEMM(prot_emb, dt1_W, dt1_b, W4, 256, 0);                       // proj_p
  hipMemsetAsync(W5, 0, NB * 4, stream);
  hipLaunchKernelGGL(scatter_sum, egridT, blk, 0, stream, dti + EDTI, dti, W4, W5, EDTI);
  GEMM(drug_emb, dr1_W, dr1_b, W4, 256, 0);                       // lin (proj dead)
  COMB(W3, W1, dinvD, dd1_b, W4, W5, icD, nullptr, nullptr, W1, DN, 1);

  // ---- P4p (protein layer 1): p -> W3 ----
  GEMM(prot_emb, pp1_W, nullptr, W3, 256, 0);
  hipMemsetAsync(W4, 0, NB * 4, stream);
  hipLaunchKernelGGL(scatter_gcn, egridP, blk, 0, stream, ppi, ppi + EPPI, dinvP, W3, W4, EPPI);
  GEMM(drug_emb, td1_W, td1_b, W5, 256, 0);                       // proj_d
  hipMemsetAsync(W6, 0, NB * 4, stream);
  hipLaunchKernelGGL(scatter_sum, egridT, blk, 0, stream, dti, dti + EDTI, W5, W6, EDTI);
  GEMM(prot_emb, pr1_W, pr1_b, W5, 256, 0);                       // lin (proj dead)
  COMB(W4, W3, dinvP, pp1_b, W5, W6, icP, nullptr, nullptr, W3, PN, 1);

  // ---- P5 (protein layer 2): p2 -> W1 ----
  GEMM(W1, td2_W, td2_b, W4, 256, 0);                             // proj from d (W1)
  hipMemsetAsync(W5, 0, NB * 4, stream);
  hipLaunchKernelGGL(scatter_sum, egridT, blk, 0, stream, dti, dti + EDTI, W4, W5, EDTI);
  GEMM(W3, pp2_W, nullptr, W1, 256, 0);                           // t (d dead)
  hipMemsetAsync(W4, 0, NB * 4, stream);
  hipLaunchKernelGGL(scatter_gcn, egridP, blk, 0, stream, ppi, ppi + EPPI, dinvP, W1, W4, EPPI);
  GEMM(W3, pr2_W, pr2_b, W6, 256, 0);                             // lin
  COMB(W4, W1, dinvP, pp2_b, W6, W5, icP, nullptr, nullptr, W1, PN, 0);

  // ---- P6: fuse precompute ----
  COMB(W0, nullptr, nullptr, nullptr, nullptr, nullptr, nullptr, nullptr, nullptr, W3, PN, 2); // fp = elu(LN(x_seq))
  GEMM(W3, seq_fc_W, nullptr, W4, 256, 2);                        // x_fp = elu(fp @ seq_fc^T)
  GEMM(prot_emb, skip_fc_W, nullptr, W5, 256, 0);                 // x_skip

  // ---- P7: pair epilogue ----
  hipLaunchKernelGGL(pair_kernel, dim3((NPAIRN + 3) / 4), blk, 0, stream,
                     W2, W4, W1, W5, idx1, idx2, wR, wI, outp, NPAIRN);
}

// Round 2
// 2334.628 us; speedup vs baseline: 6.9473x; 6.9473x over previous
//
#include <hip/hip_runtime.h>
#include <math.h>

#define PN 20000
#define DN 20000
#define SEQK 1024
#define EPPI 640000
#define EDDI 640000
#define EDTI 400000
#define NPAIRN 100000

typedef float4 f4;

__device__ __forceinline__ f4 ld4(const float* p) { return *reinterpret_cast<const f4*>(p); }
__device__ __forceinline__ void st4(float* p, f4 v) { *reinterpret_cast<f4*>(p) = v; }
__device__ __forceinline__ void acc4(f4& a, f4 b) { a.x+=b.x; a.y+=b.y; a.z+=b.z; a.w+=b.w; }
__device__ __forceinline__ void acc4s(f4& a, f4 b, float s) { a.x+=s*b.x; a.y+=s*b.y; a.z+=s*b.z; a.w+=s*b.w; }

// LayerNorm over a 256-wide row held as one float4 per lane across a 64-lane wave.
__device__ __forceinline__ void wave_ln(f4& x) {
  float s  = x.x + x.y + x.z + x.w;
  float ss = x.x*x.x + x.y*x.y + x.z*x.z + x.w*x.w;
#pragma unroll
  for (int o = 32; o; o >>= 1) { s += __shfl_xor(s, o, 64); ss += __shfl_xor(ss, o, 64); }
  float m = s * (1.f/256.f);
  float v = ss * (1.f/256.f) - m*m;
  float r = rsqrtf(v + 1e-5f);
  x.x = (x.x-m)*r; x.y = (x.y-m)*r; x.z = (x.z-m)*r; x.w = (x.w-m)*r;
}

// ---------------- GEMM: out[N,256] = X[N,K] @ Wt[256,K]^T (+bias)(+act) ----------------
// act: 0 none, 1 relu, 2 elu
__global__ __launch_bounds__(256) void gemm_nt(
    const float* __restrict__ X, const float* __restrict__ Wt,
    const float* __restrict__ bias, float* __restrict__ out,
    int N, int K, int act)
{
  __shared__ float Xs[64][17];
  __shared__ float Ws[64][17];
  const int tid = threadIdx.x;
  const int r0 = blockIdx.x * 64;
  const int c0 = blockIdx.y * 64;
  const int tx = tid & 15, ty = tid >> 4;
  const int lr = tid >> 2;          // load row 0..63
  const int lk = (tid & 3) * 4;     // load k-chunk 0,4,8,12
  float acc[4][4] = {};
  for (int k0 = 0; k0 < K; k0 += 16) {
    int xr = r0 + lr;
    f4 xv = make_float4(0.f,0.f,0.f,0.f);
    if (xr < N) xv = ld4(X + (size_t)xr * K + k0 + lk);
    Xs[lr][lk+0]=xv.x; Xs[lr][lk+1]=xv.y; Xs[lr][lk+2]=xv.z; Xs[lr][lk+3]=xv.w;
    f4 wv = ld4(Wt + (size_t)(c0 + lr) * K + k0 + lk);
    Ws[lr][lk+0]=wv.x; Ws[lr][lk+1]=wv.y; Ws[lr][lk+2]=wv.z; Ws[lr][lk+3]=wv.w;
    __syncthreads();
#pragma unroll
    for (int k = 0; k < 16; ++k) {
      float xr4[4], wc4[4];
#pragma unroll
      for (int i = 0; i < 4; ++i) xr4[i] = Xs[ty*4+i][k];
#pragma unroll
      for (int j = 0; j < 4; ++j) wc4[j] = Ws[tx*4+j][k];
#pragma unroll
      for (int i = 0; i < 4; ++i)
#pragma unroll
        for (int j = 0; j < 4; ++j) acc[i][j] += xr4[i]*wc4[j];
    }
    __syncthreads();
  }
#pragma unroll
  for (int i = 0; i < 4; ++i) {
    int r = r0 + ty*4 + i;
    if (r >= N) continue;
    f4 o;
    float* po = &o.x;
#pragma unroll
    for (int j = 0; j < 4; ++j) {
      int c = c0 + tx*4 + j;
      float v = acc[i][j];
      if (bias) v += bias[c];
      if (act == 1) v = fmaxf(v, 0.f);
      else if (act == 2) v = v > 0.f ? v : (expf(v) - 1.f);
      po[j] = v;
    }
    st4(out + (size_t)r * 256 + c0 + tx*4, o);
  }
}

// ---------------- degree / count ----------------
__global__ __launch_bounds__(256) void count_kernel(const int* __restrict__ idx, int* __restrict__ cnt, int n) {
  int i = blockIdx.x * 256 + threadIdx.x;
  if (i < n) atomicAdd(&cnt[idx[i]], 1);
}

__global__ __launch_bounds__(256) void finalize_deg(
    const int* __restrict__ degP, const int* __restrict__ degD,
    const int* __restrict__ cntD, const int* __restrict__ cntP,
    float* __restrict__ dinvP, float* __restrict__ dinvD,
    float* __restrict__ icD, float* __restrict__ icP, int n)
{
  int i = blockIdx.x * 256 + threadIdx.x;
  if (i < n) {
    dinvP[i] = rsqrtf((float)degP[i] + 1.f);  // +1 = self loop
    dinvD[i] = rsqrtf((float)degD[i] + 1.f);
    icD[i] = 1.f / fmaxf((float)cntD[i], 1.f);
    icP[i] = 1.f / fmaxf((float)cntP[i], 1.f);
  }
}

// ---------------- single-block exclusive scan: rowptr[0..n] from cnt[0..n-1]; cur = rowptr copy ----
__global__ __launch_bounds__(1024) void scan_kernel(
    const int* __restrict__ cnt, int* __restrict__ rowptr, int* __restrict__ cur, int n)
{
  __shared__ int sums[1024];
  const int t = threadIdx.x;
  const int chunk = (n + 1023) / 1024;
  const int b = t * chunk;
  const int e = min(b + chunk, n);
  int s = 0;
  for (int i = b; i < e; ++i) s += cnt[i];
  sums[t] = s;
  __syncthreads();
  for (int o = 1; o < 1024; o <<= 1) {
    int u = (t >= o) ? sums[t - o] : 0;
    __syncthreads();
    sums[t] += u;
    __syncthreads();
  }
  int run = sums[t] - s;   // exclusive offset
  for (int i = b; i < e; ++i) { rowptr[i] = run; cur[i] = run; run += cnt[i]; }
  if (t == 1023) rowptr[n] = sums[1023];
}

// ---------------- CSR fill: col[pos] = src, pos allocated by atomic cursor on dst ----------------
__global__ __launch_bounds__(256) void fill_kernel(
    const int* __restrict__ src, const int* __restrict__ dst,
    int* __restrict__ cur, int* __restrict__ col, int nE)
{
  int e = blockIdx.x * 256 + threadIdx.x;
  if (e < nE) {
    int d = dst[e];
    int pos = atomicAdd(&cur[d], 1);
    col[pos] = src[e];
  }
}

// ---------------- GCN gather: A[d] = sum_j dinv[col[j]]*dinv[d] * T[col[j]] ----------------
__global__ __launch_bounds__(256) void gather_gcn(
    const int* __restrict__ rowptr, const int* __restrict__ col,
    const float* __restrict__ dinv, const float* __restrict__ T,
    float* __restrict__ A, int n)
{
  int row = (blockIdx.x * blockDim.x + threadIdx.x) >> 6;
  if (row >= n) return;
  int lane = threadIdx.x & 63;
  int beg = rowptr[row], end = rowptr[row + 1];
  float dd = dinv[row];
  f4 a = make_float4(0.f, 0.f, 0.f, 0.f);
  int j = beg;
  for (; j + 1 < end; j += 2) {
    int s0 = col[j], s1 = col[j + 1];
    float n0 = dd * dinv[s0], n1 = dd * dinv[s1];
    f4 t0 = ld4(T + (size_t)s0 * 256 + lane * 4);
    f4 t1 = ld4(T + (size_t)s1 * 256 + lane * 4);
    acc4s(a, t0, n0);
    acc4s(a, t1, n1);
  }
  if (j < end) {
    int s0 = col[j];
    acc4s(a, ld4(T + (size_t)s0 * 256 + lane * 4), dd * dinv[s0]);
  }
  st4(A + (size_t)row * 256 + lane * 4, a);
}

// ---------------- plain gather-sum (for scatter_mean numerator) ----------------
__global__ __launch_bounds__(256) void gather_sum(
    const int* __restrict__ rowptr, const int* __restrict__ col,
    const float* __restrict__ T, float* __restrict__ S, int n)
{
  int row = (blockIdx.x * blockDim.x + threadIdx.x) >> 6;
  if (row >= n) return;
  int lane = threadIdx.x & 63;
  int beg = rowptr[row], end = rowptr[row + 1];
  f4 a = make_float4(0.f, 0.f, 0.f, 0.f);
  int j = beg;
  for (; j + 1 < end; j += 2) {
    int s0 = col[j], s1 = col[j + 1];
    f4 t0 = ld4(T + (size_t)s0 * 256 + lane * 4);
    f4 t1 = ld4(T + (size_t)s1 * 256 + lane * 4);
    acc4(a, t0);
    acc4(a, t1);
  }
  if (j < end) acc4(a, ld4(T + (size_t)col[j] * 256 + lane * 4));
  st4(S + (size_t)row * 256 + lane * 4, a);
}

// ---------------- combine: out = act( LN( A + dinv^2*T + gb + L + ic*S ) [*lw+lb] ) ----------------
__global__ __launch_bounds__(256) void combine_ln(
    const float* __restrict__ A, const float* __restrict__ T, const float* __restrict__ dinv,
    const float* __restrict__ gb, const float* __restrict__ L,
    const float* __restrict__ S, const float* __restrict__ ic,
    const float* __restrict__ lw, const float* __restrict__ lb,
    float* __restrict__ out, int n, int act)
{
  int row = (blockIdx.x * blockDim.x + threadIdx.x) >> 6;
  if (row >= n) return;
  int lane = threadIdx.x & 63;
  size_t base = (size_t)row * 256 + lane*4;
  f4 x = make_float4(0.f,0.f,0.f,0.f);
  if (A) acc4(x, ld4(A + base));
  if (T) { float dv = dinv[row]; acc4s(x, ld4(T + base), dv*dv); }
  if (gb) acc4(x, ld4(gb + lane*4));
  if (L) acc4(x, ld4(L + base));
  if (S) acc4s(x, ld4(S + base), ic[row]);
  wave_ln(x);
  if (lw) {
    f4 w = ld4(lw + lane*4), b = ld4(lb + lane*4);
    x.x = x.x*w.x + b.x; x.y = x.y*w.y + b.y; x.z = x.z*w.z + b.z; x.w = x.w*w.w + b.w;
  }
  if (act == 1) {
    x.x = fmaxf(x.x, 0.f); x.y = fmaxf(x.y, 0.f); x.z = fmaxf(x.z, 0.f); x.w = fmaxf(x.w, 0.f);
  } else if (act == 2) {
    x.x = x.x > 0.f ? x.x : expf(x.x)-1.f;
    x.y = x.y > 0.f ? x.y : expf(x.y)-1.f;
    x.z = x.z > 0.f ? x.z : expf(x.z)-1.f;
    x.w = x.w > 0.f ? x.w : expf(x.w)-1.f;
  }
  st4(out + base, x);
}

// ---------------- pair epilogue: complex fuse, one wave per pair ----------------
__global__ __launch_bounds__(256) void pair_kernel(
    const float* __restrict__ x1, const float* __restrict__ xfp,
    const float* __restrict__ p2, const float* __restrict__ xskip,
    const int* __restrict__ idx1, const int* __restrict__ idx2,
    const float* __restrict__ wR, const float* __restrict__ wI,
    float* __restrict__ out, int npair)
{
  int wid = (blockIdx.x * blockDim.x + threadIdx.x) >> 6;
  if (wid >= npair) return;
  int lane = threadIdx.x & 63;
  int f = lane * 4;
  size_t o1 = (size_t)idx1[wid] * 256 + f;
  size_t o2 = (size_t)idx2[wid] * 256 + f;

  f4 R1 = ld4(x1 + o1);    acc4(R1, ld4(xfp + o2));   wave_ln(R1);
  f4 I1 = ld4(p2 + o1);    acc4(I1, ld4(xskip + o2)); wave_ln(I1);
  f4 R2 = ld4(xskip + o1); acc4(R2, ld4(p2 + o2));    wave_ln(R2);
  f4 I2 = ld4(xfp + o1);   acc4(I2, ld4(x1 + o2));    wave_ln(I2);

  f4 R, I;
  R.x = R1.x*R2.x - I1.x*I2.x;  I.x = R1.x*I2.x + I1.x*R2.x;
  R.y = R1.y*R2.y - I1.y*I2.y;  I.y = R1.y*I2.y + I1.y*R2.y;
  R.z = R1.z*R2.z - I1.z*I2.z;  I.z = R1.z*I2.z + I1.z*R2.z;
  R.w = R1.w*R2.w - I1.w*I2.w;  I.w = R1.w*I2.w + I1.w*R2.w;
  wave_ln(R); wave_ln(I);

  f4 wr = ld4(wR + f), wi = ld4(wI + f);
  float r_ = R.x*wr.x + I.x*wi.x + R.y*wr.y + I.y*wi.y
           + R.z*wr.z + I.z*wi.z + R.w*wr.w + I.w*wi.w;
  float i_ = I.x*wr.x - R.x*wi.x + I.y*wr.y - R.y*wi.y
           + I.z*wr.z - R.z*wi.z + I.w*wr.w - R.w*wi.w;
  float t = r_ + i_;
#pragma unroll
  for (int o = 32; o; o >>= 1) t += __shfl_xor(t, o, 64);
  if (lane == 0) out[wid] = 1.f / (1.f + expf(-t));
}

extern "C" void kernel_launch(void* const* d_in, const int* in_sizes, int n_in,
                              void* d_out, int out_size, void* d_ws, size_t ws_size,
                              hipStream_t stream) {
  (void)in_sizes; (void)n_in; (void)out_size; (void)ws_size;
  const float* seq        = (const float*)d_in[0];
  const int*   ppi        = (const int*)d_in[1];
  const int*   ddi        = (const int*)d_in[2];
  const int*   dti        = (const int*)d_in[3];
  const int*   idx1       = (const int*)d_in[4];
  const int*   idx2       = (const int*)d_in[5];
  const float* seq_init_W = (const float*)d_in[6];
  const float* gs1_gcn_W  = (const float*)d_in[7];
  const float* gs1_gcn_b  = (const float*)d_in[8];
  const float* gs1_lin_W  = (const float*)d_in[9];
  const float* gs1_ln_w   = (const float*)d_in[10];
  const float* gs1_ln_b   = (const float*)d_in[11];
  const float* gs2_gcn_W  = (const float*)d_in[12];
  const float* gs2_gcn_b  = (const float*)d_in[13];
  const float* gs2_lin_W  = (const float*)d_in[14];
  const float* gs2_ln_w   = (const float*)d_in[15];
  const float* gs2_ln_b   = (const float*)d_in[16];
  const float* drug_emb   = (const float*)d_in[17];
  const float* prot_emb   = (const float*)d_in[18];
  const float* pp1_W = (const float*)d_in[19]; const float* pp1_b = (const float*)d_in[20];
  const float* td1_W = (const float*)d_in[21]; const float* td1_b = (const float*)d_in[22];
  const float* pr1_W = (const float*)d_in[23]; const float* pr1_b = (const float*)d_in[24];
  const float* dd1_W = (const float*)d_in[25]; const float* dd1_b = (const float*)d_in[26];
  const float* dt1_W = (const float*)d_in[27]; const float* dt1_b = (const float*)d_in[28];
  const float* dr1_W = (const float*)d_in[29]; const float* dr1_b = (const float*)d_in[30];
  const float* pp2_W = (const float*)d_in[31]; const float* pp2_b = (const float*)d_in[32];
  const float* td2_W = (const float*)d_in[33]; const float* td2_b = (const float*)d_in[34];
  const float* pr2_W = (const float*)d_in[35]; const float* pr2_b = (const float*)d_in[36];
  // d_in[37..42]: dd2/dt2/dr2 — dead code in ASC path
  const float* seq_fc_W  = (const float*)d_in[43];
  const float* skip_fc_W = (const float*)d_in[44];
  const float* wR = (const float*)d_in[45];
  const float* wI = (const float*)d_in[46];
  float* outp = (float*)d_out;

  float* ws = (float*)d_ws;
  const size_t NB = (size_t)PN * 256;
  float* W0 = ws + 0*NB;  // x_seq
  float* W1 = ws + 1*NB;
  float* W2 = ws + 2*NB;
  float* W3 = ws + 3*NB;
  float* W4 = ws + 4*NB;
  float* W5 = ws + 5*NB;
  float* W6 = ws + 6*NB;
  int*   ib   = (int*)(ws + 7*NB);
  int*   degP = ib;             // counts, contiguous block of 4*PN for one memset
  int*   degD = degP + PN;
  int*   cntD = degD + DN;
  int*   cntP = cntD + DN;
  float* dinvP = (float*)(cntP + PN);
  float* dinvD = dinvP + PN;
  float* icD   = dinvD + DN;
  float* icP   = icD + DN;
  int* rowptrP  = (int*)(icP + PN);
  int* rowptrD  = rowptrP  + PN + 1;
  int* rowptrTD = rowptrD  + DN + 1;
  int* rowptrTP = rowptrTD + DN + 1;
  int* curP  = rowptrTP + PN + 1;
  int* curD  = curP + PN;
  int* curTD = curD + DN;
  int* curTP = curTD + DN;
  int* colP  = curTP + PN;      // EPPI
  int* colD  = colP + EPPI;     // EDDI
  int* colTD = colD + EDDI;     // EDTI
  int* colTP = colTD + EDTI;    // EDTI

  const dim3 blk(256);
  const dim3 ggrid(313, 4);             // ceil(20000/64) x 256/64
  const dim3 rgrid((PN + 3) / 4);       // wave-per-row kernels: 4 rows/block
  const dim3 fgridP((EPPI + 255) / 256);
  const dim3 fgridD((EDDI + 255) / 256);
  const dim3 fgridT((EDTI + 255) / 256);

  auto GEMM = [&](const float* X, const float* Wt, const float* bias, float* o, int K, int act) {
    hipLaunchKernelGGL(gemm_nt, ggrid, blk, 0, stream, X, Wt, bias, o, PN, K, act);
  };
  auto COMB = [&](const float* A, const float* T, const float* dv, const float* gb,
                  const float* L, const float* S, const float* ic,
                  const float* lw, const float* lb, float* o, int n, int act) {
    hipLaunchKernelGGL(combine_ln, rgrid, blk, 0, stream, A, T, dv, gb, L, S, ic, lw, lb, o, n, act);
  };
  auto GGCN = [&](const int* rp, const int* cl, const float* dv, const float* T, float* A) {
    hipLaunchKernelGGL(gather_gcn, rgrid, blk, 0, stream, rp, cl, dv, T, A, PN);
  };
  auto GSUM = [&](const int* rp, const int* cl, const float* T, float* S) {
    hipLaunchKernelGGL(gather_sum, rgrid, blk, 0, stream, rp, cl, T, S, PN);
  };

  // ---- degrees & counts ----
  hipMemsetAsync(degP, 0, 4 * sizeof(int) * PN, stream);
  hipLaunchKernelGGL(count_kernel, fgridP, blk, 0, stream, ppi + EPPI, degP, EPPI);
  hipLaunchKernelGGL(count_kernel, fgridD, blk, 0, stream, ddi + EDDI, degD, EDDI);
  hipLaunchKernelGGL(count_kernel, fgridT, blk, 0, stream, dti,        cntD, EDTI);
  hipLaunchKernelGGL(count_kernel, fgridT, blk, 0, stream, dti + EDTI, cntP, EDTI);
  hipLaunchKernelGGL(finalize_deg, dim3((PN+255)/256), blk, 0, stream,
                     degP, degD, cntD, cntP, dinvP, dinvD, icD, icP, PN);

  // ---- CSR build (by destination) ----
  hipLaunchKernelGGL(scan_kernel, dim3(1), dim3(1024), 0, stream, degP, rowptrP,  curP,  PN);
  hipLaunchKernelGGL(scan_kernel, dim3(1), dim3(1024), 0, stream, degD, rowptrD,  curD,  DN);
  hipLaunchKernelGGL(scan_kernel, dim3(1), dim3(1024), 0, stream, cntD, rowptrTD, curTD, DN);
  hipLaunchKernelGGL(scan_kernel, dim3(1), dim3(1024), 0, stream, cntP, rowptrTP, curTP, PN);
  hipLaunchKernelGGL(fill_kernel, fgridP, blk, 0, stream, ppi,        ppi + EPPI, curP,  colP,  EPPI);
  hipLaunchKernelGGL(fill_kernel, fgridD, blk, 0, stream, ddi,        ddi + EDDI, curD,  colD,  EDDI);
  hipLaunchKernelGGL(fill_kernel, fgridT, blk, 0, stream, dti + EDTI, dti,        curTD, colTD, EDTI);
  hipLaunchKernelGGL(fill_kernel, fgridT, blk, 0, stream, dti,        dti + EDTI, curTP, colTP, EDTI);

  // ---- P1: x_seq = relu(seq @ seq_init_W^T) -> W0 ----
  GEMM(seq, seq_init_W, nullptr, W0, SEQK, 1);

  // ---- P2 (gs1): h -> W1 ----
  GEMM(W0, gs1_gcn_W, nullptr, W1, 256, 0);                       // t
  GGCN(rowptrP, colP, dinvP, W1, W2);
  GEMM(W0, gs1_lin_W, nullptr, W3, 256, 0);                       // lin
  COMB(W2, W1, dinvP, gs1_gcn_b, W3, nullptr, nullptr, gs1_ln_w, gs1_ln_b, W1, PN, 1);

  // ---- P3 (gs2): x1 -> W2 ----
  GEMM(W1, gs2_gcn_W, nullptr, W2, 256, 0);
  GGCN(rowptrP, colP, dinvP, W2, W3);
  GEMM(W1, gs2_lin_W, nullptr, W4, 256, 0);
  COMB(W3, W2, dinvP, gs2_gcn_b, W4, nullptr, nullptr, gs2_ln_w, gs2_ln_b, W2, PN, 0);

  // ---- P4d (drug layer 1): d -> W1 ----
  GEMM(drug_emb, dd1_W, nullptr, W1, 256, 0);
  GGCN(rowptrD, colD, dinvD, W1, W3);
  GEMM(prot_emb, dt1_W, dt1_b, W4, 256, 0);                       // proj_p
  GSUM(rowptrTD, colTD, W4, W5);
  GEMM(drug_emb, dr1_W, dr1_b, W4, 256, 0);                       // lin
  COMB(W3, W1, dinvD, dd1_b, W4, W5, icD, nullptr, nullptr, W1, DN, 1);

  // ---- P4p (protein layer 1): p -> W3 ----
  GEMM(prot_emb, pp1_W, nullptr, W3, 256, 0);
  GGCN(rowptrP, colP, dinvP, W3, W4);
  GEMM(drug_emb, td1_W, td1_b, W5, 256, 0);                       // proj_d
  GSUM(rowptrTP, colTP, W5, W6);
  GEMM(prot_emb, pr1_W, pr1_b, W5, 256, 0);                       // lin
  COMB(W4, W3, dinvP, pp1_b, W5, W6, icP, nullptr, nullptr, W3, PN, 1);

  // ---- P5 (protein layer 2): p2 -> W1 ----
  GEMM(W1, td2_W, td2_b, W4, 256, 0);                             // proj from d (W1)
  GSUM(rowptrTP, colTP, W4, W5);
  GEMM(W3, pp2_W, nullptr, W1, 256, 0);                           // t
  GGCN(rowptrP, colP, dinvP, W1, W4);
  GEMM(W3, pr2_W, pr2_b, W6, 256, 0);                             // lin
  COMB(W4, W1, dinvP, pp2_b, W6, W5, icP, nullptr, nullptr, W1, PN, 0);

  // ---- P6: fuse precompute ----
  COMB(W0, nullptr, nullptr, nullptr, nullptr, nullptr, nullptr, nullptr, nullptr, W3, PN, 2); // fp = elu(LN(x_seq))
  GEMM(W3, seq_fc_W, nullptr, W4, 256, 2);                        // x_fp
  GEMM(prot_emb, skip_fc_W, nullptr, W5, 256, 0);                 // x_skip

  // ---- P7: pair epilogue ----
  hipLaunchKernelGGL(pair_kernel, dim3((NPAIRN + 3) / 4), blk, 0, stream,
                     W2, W4, W1, W5, idx1, idx2, wR, wI, outp, NPAIRN);
}

// Round 3
// 1699.874 us; speedup vs baseline: 9.5415x; 1.3734x over previous
//
#include <hip/hip_runtime.h>
#include <hip/hip_bf16.h>
#include <math.h>

#define PN 20000
#define DN 20000
#define SEQK 1024
#define EPPI 640000
#define EDDI 640000
#define EDTI 400000
#define NPAIRN 100000

typedef float4 f4;
using bf16x8 = __attribute__((ext_vector_type(8))) __bf16;
using f32x4v = __attribute__((ext_vector_type(4))) float;

__device__ __forceinline__ f4 ld4(const float* p) { return *reinterpret_cast<const f4*>(p); }
__device__ __forceinline__ void st4(float* p, f4 v) { *reinterpret_cast<f4*>(p) = v; }
__device__ __forceinline__ void acc4(f4& a, f4 b) { a.x+=b.x; a.y+=b.y; a.z+=b.z; a.w+=b.w; }
__device__ __forceinline__ void acc4s(f4& a, f4 b, float s) { a.x+=s*b.x; a.y+=s*b.y; a.z+=s*b.z; a.w+=s*b.w; }

// LayerNorm over a 256-wide row held as one float4 per lane across a 64-lane wave.
__device__ __forceinline__ void wave_ln(f4& x) {
  float s  = x.x + x.y + x.z + x.w;
  float ss = x.x*x.x + x.y*x.y + x.z*x.z + x.w*x.w;
#pragma unroll
  for (int o = 32; o; o >>= 1) { s += __shfl_xor(s, o, 64); ss += __shfl_xor(ss, o, 64); }
  float m = s * (1.f/256.f);
  float v = ss * (1.f/256.f) - m*m;
  float r = rsqrtf(v + 1e-5f);
  x.x = (x.x-m)*r; x.y = (x.y-m)*r; x.z = (x.z-m)*r; x.w = (x.w-m)*r;
}

__device__ __forceinline__ bf16x8 cvt8(const float* p) {
  f4 u = ld4(p), v = ld4(p + 4);
  bf16x8 r;
  r[0] = (__bf16)u.x; r[1] = (__bf16)u.y; r[2] = (__bf16)u.z; r[3] = (__bf16)u.w;
  r[4] = (__bf16)v.x; r[5] = (__bf16)v.y; r[6] = (__bf16)v.z; r[7] = (__bf16)v.w;
  return r;
}

// ---------------- weight pre-convert: fp32 -> bf16, 16 weights in one launch ----------------
struct WPack {
  const float* src[16];
  __bf16* dst[16];
  int n[16];
};

__global__ __launch_bounds__(256) void convert_weights(WPack p) {
  const int wi = blockIdx.y;
  const int n = p.n[wi];
  const float* s = p.src[wi];
  __bf16* d = p.dst[wi];
  for (int i = (blockIdx.x * 256 + threadIdx.x) * 4; i < n; i += gridDim.x * 256 * 4) {
    f4 v = ld4(s + i);
    ushort4 o;
    o.x = __builtin_bit_cast(unsigned short, (__bf16)v.x);
    o.y = __builtin_bit_cast(unsigned short, (__bf16)v.y);
    o.z = __builtin_bit_cast(unsigned short, (__bf16)v.z);
    o.w = __builtin_bit_cast(unsigned short, (__bf16)v.w);
    *reinterpret_cast<ushort4*>(d + i) = o;
  }
}

// ---------------- MFMA GEMM: out[M,256] = X[M,K](fp32,cvt) @ Wt[256,K](bf16)^T (+bias)(+act) ----
// Block: 256 thr = 4 waves; wave (w>>1, w&1) owns 32 rows x 128 cols. Grid: ceil(M/64).
// No LDS: A fragments converted in-kernel; B fragments are direct 16B loads (L2-resident).
__global__ __launch_bounds__(256) void gemm_mfma(
    const float* __restrict__ X, const __bf16* __restrict__ Wt,
    const float* __restrict__ bias, float* __restrict__ out,
    int M, int K, int act)
{
  const int tid = threadIdx.x;
  const int lane = tid & 63;
  const int w = tid >> 6;
  const int wr = (w >> 1) * 32;
  const int wc = (w & 1) * 128;
  const int r0 = blockIdx.x * 64 + wr;
  const int l15 = lane & 15;
  const int lk = (lane >> 4) * 8;

  f32x4v acc[2][8];
#pragma unroll
  for (int m = 0; m < 2; ++m)
#pragma unroll
    for (int n = 0; n < 8; ++n) { acc[m][n][0]=0.f; acc[m][n][1]=0.f; acc[m][n][2]=0.f; acc[m][n][3]=0.f; }

  int ra = r0 + l15;      if (ra > M - 1) ra = M - 1;
  int rb = r0 + 16 + l15; if (rb > M - 1) rb = M - 1;
  const float* xa = X + (size_t)ra * K + lk;
  const float* xb = X + (size_t)rb * K + lk;
  const __bf16* wp = Wt + (size_t)(wc + l15) * K + lk;

  for (int k0 = 0; k0 < K; k0 += 32) {
    bf16x8 a0 = cvt8(xa + k0);
    bf16x8 a1 = cvt8(xb + k0);
#pragma unroll
    for (int n = 0; n < 8; ++n) {
      bf16x8 b = *reinterpret_cast<const bf16x8*>(wp + (size_t)n * 16 * K + k0);
      acc[0][n] = __builtin_amdgcn_mfma_f32_16x16x32_bf16(a0, b, acc[0][n], 0, 0, 0);
      acc[1][n] = __builtin_amdgcn_mfma_f32_16x16x32_bf16(a1, b, acc[1][n], 0, 0, 0);
    }
  }

  const int rowbase = r0 + (lane >> 4) * 4;
#pragma unroll
  for (int m = 0; m < 2; ++m) {
#pragma unroll
    for (int i = 0; i < 4; ++i) {
      int row = rowbase + m * 16 + i;
      if (row >= M) continue;
      float* po = out + (size_t)row * 256 + wc + l15;
#pragma unroll
      for (int n = 0; n < 8; ++n) {
        float v = acc[m][n][i];
        if (bias) v += bias[wc + n * 16 + l15];
        if (act == 1) v = fmaxf(v, 0.f);
        else if (act == 2) v = v > 0.f ? v : (expf(v) - 1.f);
        po[n * 16] = v;
      }
    }
  }
}

// ---------------- degree / count ----------------
__global__ __launch_bounds__(256) void count_kernel(const int* __restrict__ idx, int* __restrict__ cnt, int n) {
  int i = blockIdx.x * 256 + threadIdx.x;
  if (i < n) atomicAdd(&cnt[idx[i]], 1);
}

__global__ __launch_bounds__(256) void finalize_deg(
    const int* __restrict__ degP, const int* __restrict__ degD,
    const int* __restrict__ cntD, const int* __restrict__ cntP,
    float* __restrict__ dinvP, float* __restrict__ dinvD,
    float* __restrict__ icD, float* __restrict__ icP, int n)
{
  int i = blockIdx.x * 256 + threadIdx.x;
  if (i < n) {
    dinvP[i] = rsqrtf((float)degP[i] + 1.f);  // +1 = self loop
    dinvD[i] = rsqrtf((float)degD[i] + 1.f);
    icD[i] = 1.f / fmaxf((float)cntD[i], 1.f);
    icP[i] = 1.f / fmaxf((float)cntP[i], 1.f);
  }
}

// ---------------- single-block exclusive scan: rowptr[0..n] from cnt[0..n-1]; cur = rowptr copy ----
__global__ __launch_bounds__(1024) void scan_kernel(
    const int* __restrict__ cnt, int* __restrict__ rowptr, int* __restrict__ cur, int n)
{
  __shared__ int sums[1024];
  const int t = threadIdx.x;
  const int chunk = (n + 1023) / 1024;
  const int b = t * chunk;
  const int e = min(b + chunk, n);
  int s = 0;
  for (int i = b; i < e; ++i) s += cnt[i];
  sums[t] = s;
  __syncthreads();
  for (int o = 1; o < 1024; o <<= 1) {
    int u = (t >= o) ? sums[t - o] : 0;
    __syncthreads();
    sums[t] += u;
    __syncthreads();
  }
  int run = sums[t] - s;   // exclusive offset
  for (int i = b; i < e; ++i) { rowptr[i] = run; cur[i] = run; run += cnt[i]; }
  if (t == 1023) rowptr[n] = sums[1023];
}

// ---------------- CSR fill: col[pos] = src, pos allocated by atomic cursor on dst ----------------
__global__ __launch_bounds__(256) void fill_kernel(
    const int* __restrict__ src, const int* __restrict__ dst,
    int* __restrict__ cur, int* __restrict__ col, int nE)
{
  int e = blockIdx.x * 256 + threadIdx.x;
  if (e < nE) {
    int d = dst[e];
    int pos = atomicAdd(&cur[d], 1);
    col[pos] = src[e];
  }
}

// ---------------- GCN gather: A[d] = sum_j dinv[col[j]]*dinv[d] * T[col[j]] ----------------
__global__ __launch_bounds__(256) void gather_gcn(
    const int* __restrict__ rowptr, const int* __restrict__ col,
    const float* __restrict__ dinv, const float* __restrict__ T,
    float* __restrict__ A, int n)
{
  int row = (blockIdx.x * blockDim.x + threadIdx.x) >> 6;
  if (row >= n) return;
  int lane = threadIdx.x & 63;
  int beg = rowptr[row], end = rowptr[row + 1];
  float dd = dinv[row];
  f4 a = make_float4(0.f, 0.f, 0.f, 0.f);
  int j = beg;
  for (; j + 1 < end; j += 2) {
    int s0 = col[j], s1 = col[j + 1];
    float n0 = dd * dinv[s0], n1 = dd * dinv[s1];
    f4 t0 = ld4(T + (size_t)s0 * 256 + lane * 4);
    f4 t1 = ld4(T + (size_t)s1 * 256 + lane * 4);
    acc4s(a, t0, n0);
    acc4s(a, t1, n1);
  }
  if (j < end) {
    int s0 = col[j];
    acc4s(a, ld4(T + (size_t)s0 * 256 + lane * 4), dd * dinv[s0]);
  }
  st4(A + (size_t)row * 256 + lane * 4, a);
}

// ---------------- plain gather-sum (for scatter_mean numerator) ----------------
__global__ __launch_bounds__(256) void gather_sum(
    const int* __restrict__ rowptr, const int* __restrict__ col,
    const float* __restrict__ T, float* __restrict__ S, int n)
{
  int row = (blockIdx.x * blockDim.x + threadIdx.x) >> 6;
  if (row >= n) return;
  int lane = threadIdx.x & 63;
  int beg = rowptr[row], end = rowptr[row + 1];
  f4 a = make_float4(0.f, 0.f, 0.f, 0.f);
  int j = beg;
  for (; j + 1 < end; j += 2) {
    int s0 = col[j], s1 = col[j + 1];
    f4 t0 = ld4(T + (size_t)s0 * 256 + lane * 4);
    f4 t1 = ld4(T + (size_t)s1 * 256 + lane * 4);
    acc4(a, t0);
    acc4(a, t1);
  }
  if (j < end) acc4(a, ld4(T + (size_t)col[j] * 256 + lane * 4));
  st4(S + (size_t)row * 256 + lane * 4, a);
}

// ---------------- combine: out = act( LN( A + dinv^2*T + gb + L + ic*S ) [*lw+lb] ) ----------------
__global__ __launch_bounds__(256) void combine_ln(
    const float* __restrict__ A, const float* __restrict__ T, const float* __restrict__ dinv,
    const float* __restrict__ gb, const float* __restrict__ L,
    const float* __restrict__ S, const float* __restrict__ ic,
    const float* __restrict__ lw, const float* __restrict__ lb,
    float* __restrict__ out, int n, int act)
{
  int row = (blockIdx.x * blockDim.x + threadIdx.x) >> 6;
  if (row >= n) return;
  int lane = threadIdx.x & 63;
  size_t base = (size_t)row * 256 + lane*4;
  f4 x = make_float4(0.f,0.f,0.f,0.f);
  if (A) acc4(x, ld4(A + base));
  if (T) { float dv = dinv[row]; acc4s(x, ld4(T + base), dv*dv); }
  if (gb) acc4(x, ld4(gb + lane*4));
  if (L) acc4(x, ld4(L + base));
  if (S) acc4s(x, ld4(S + base), ic[row]);
  wave_ln(x);
  if (lw) {
    f4 w = ld4(lw + lane*4), b = ld4(lb + lane*4);
    x.x = x.x*w.x + b.x; x.y = x.y*w.y + b.y; x.z = x.z*w.z + b.z; x.w = x.w*w.w + b.w;
  }
  if (act == 1) {
    x.x = fmaxf(x.x, 0.f); x.y = fmaxf(x.y, 0.f); x.z = fmaxf(x.z, 0.f); x.w = fmaxf(x.w, 0.f);
  } else if (act == 2) {
    x.x = x.x > 0.f ? x.x : expf(x.x)-1.f;
    x.y = x.y > 0.f ? x.y : expf(x.y)-1.f;
    x.z = x.z > 0.f ? x.z : expf(x.z)-1.f;
    x.w = x.w > 0.f ? x.w : expf(x.w)-1.f;
  }
  st4(out + base, x);
}

// ---------------- pair epilogue: complex fuse, one wave per pair ----------------
__global__ __launch_bounds__(256) void pair_kernel(
    const float* __restrict__ x1, const float* __restrict__ xfp,
    const float* __restrict__ p2, const float* __restrict__ xskip,
    const int* __restrict__ idx1, const int* __restrict__ idx2,
    const float* __restrict__ wR, const float* __restrict__ wI,
    float* __restrict__ out, int npair)
{
  int wid = (blockIdx.x * blockDim.x + threadIdx.x) >> 6;
  if (wid >= npair) return;
  int lane = threadIdx.x & 63;
  int f = lane * 4;
  size_t o1 = (size_t)idx1[wid] * 256 + f;
  size_t o2 = (size_t)idx2[wid] * 256 + f;

  f4 R1 = ld4(x1 + o1);    acc4(R1, ld4(xfp + o2));   wave_ln(R1);
  f4 I1 = ld4(p2 + o1);    acc4(I1, ld4(xskip + o2)); wave_ln(I1);
  f4 R2 = ld4(xskip + o1); acc4(R2, ld4(p2 + o2));    wave_ln(R2);
  f4 I2 = ld4(xfp + o1);   acc4(I2, ld4(x1 + o2));    wave_ln(I2);

  f4 R, I;
  R.x = R1.x*R2.x - I1.x*I2.x;  I.x = R1.x*I2.x + I1.x*R2.x;
  R.y = R1.y*R2.y - I1.y*I2.y;  I.y = R1.y*I2.y + I1.y*R2.y;
  R.z = R1.z*R2.z - I1.z*I2.z;  I.z = R1.z*I2.z + I1.z*R2.z;
  R.w = R1.w*R2.w - I1.w*I2.w;  I.w = R1.w*I2.w + I1.w*R2.w;
  wave_ln(R); wave_ln(I);

  f4 wr = ld4(wR + f), wi = ld4(wI + f);
  float r_ = R.x*wr.x + I.x*wi.x + R.y*wr.y + I.y*wi.y
           + R.z*wr.z + I.z*wi.z + R.w*wr.w + I.w*wi.w;
  float i_ = I.x*wr.x - R.x*wi.x + I.y*wr.y - R.y*wi.y
           + I.z*wr.z - R.z*wi.z + I.w*wr.w - R.w*wi.w;
  float t = r_ + i_;
#pragma unroll
  for (int o = 32; o; o >>= 1) t += __shfl_xor(t, o, 64);
  if (lane == 0) out[wid] = 1.f / (1.f + expf(-t));
}

extern "C" void kernel_launch(void* const* d_in, const int* in_sizes, int n_in,
                              void* d_out, int out_size, void* d_ws, size_t ws_size,
                              hipStream_t stream) {
  (void)in_sizes; (void)n_in; (void)out_size; (void)ws_size;
  const float* seq        = (const float*)d_in[0];
  const int*   ppi        = (const int*)d_in[1];
  const int*   ddi        = (const int*)d_in[2];
  const int*   dti        = (const int*)d_in[3];
  const int*   idx1       = (const int*)d_in[4];
  const int*   idx2       = (const int*)d_in[5];
  const float* seq_init_W = (const float*)d_in[6];
  const float* gs1_gcn_W  = (const float*)d_in[7];
  const float* gs1_gcn_b  = (const float*)d_in[8];
  const float* gs1_lin_W  = (const float*)d_in[9];
  const float* gs1_ln_w   = (const float*)d_in[10];
  const float* gs1_ln_b   = (const float*)d_in[11];
  const float* gs2_gcn_W  = (const float*)d_in[12];
  const float* gs2_gcn_b  = (const float*)d_in[13];
  const float* gs2_lin_W  = (const float*)d_in[14];
  const float* gs2_ln_w   = (const float*)d_in[15];
  const float* gs2_ln_b   = (const float*)d_in[16];
  const float* drug_emb   = (const float*)d_in[17];
  const float* prot_emb   = (const float*)d_in[18];
  const float* pp1_W = (const float*)d_in[19]; const float* pp1_b = (const float*)d_in[20];
  const float* td1_W = (const float*)d_in[21]; const float* td1_b = (const float*)d_in[22];
  const float* pr1_W = (const float*)d_in[23]; const float* pr1_b = (const float*)d_in[24];
  const float* dd1_W = (const float*)d_in[25]; const float* dd1_b = (const float*)d_in[26];
  const float* dt1_W = (const float*)d_in[27]; const float* dt1_b = (const float*)d_in[28];
  const float* dr1_W = (const float*)d_in[29]; const float* dr1_b = (const float*)d_in[30];
  const float* pp2_W = (const float*)d_in[31]; const float* pp2_b = (const float*)d_in[32];
  const float* td2_W = (const float*)d_in[33]; const float* td2_b = (const float*)d_in[34];
  const float* pr2_W = (const float*)d_in[35]; const float* pr2_b = (const float*)d_in[36];
  // d_in[37..42]: dd2/dt2/dr2 — dead code in ASC path
  const float* seq_fc_W  = (const float*)d_in[43];
  const float* skip_fc_W = (const float*)d_in[44];
  const float* wR = (const float*)d_in[45];
  const float* wI = (const float*)d_in[46];
  float* outp = (float*)d_out;

  float* ws = (float*)d_ws;
  const size_t NB = (size_t)PN * 256;
  float* W0 = ws + 0*NB;  // x_seq
  float* W1 = ws + 1*NB;
  float* W2 = ws + 2*NB;
  float* W3 = ws + 3*NB;
  float* W4 = ws + 4*NB;
  float* W5 = ws + 5*NB;
  float* W6 = ws + 6*NB;
  int*   ib   = (int*)(ws + 7*NB);
  int*   degP = ib;             // counts, contiguous block of 4*PN for one memset
  int*   degD = degP + PN;
  int*   cntD = degD + DN;
  int*   cntP = cntD + DN;
  float* dinvP = (float*)(cntP + PN);
  float* dinvD = dinvP + PN;
  float* icD   = dinvD + DN;
  float* icP   = icD + DN;
  int* rowptrP  = (int*)(icP + PN);
  int* rowptrD  = rowptrP  + PN + 1;
  int* rowptrTD = rowptrD  + DN + 1;
  int* rowptrTP = rowptrTD + DN + 1;
  int* curP  = rowptrTP + PN + 1;
  int* curD  = curP + PN;
  int* curTD = curD + DN;
  int* curTP = curTD + DN;
  int* colP  = curTP + PN;      // EPPI
  int* colD  = colP + EPPI;     // EDDI
  int* colTD = colD + EDDI;     // EDTI
  int* colTP = colTD + EDTI;    // EDTI

  // bf16 weight buffers (aligned up to 64B)
  unsigned long long waddr = (unsigned long long)(colTP + EDTI);
  waddr = (waddr + 63ULL) & ~63ULL;
  __bf16* wb = (__bf16*)waddr;
  __bf16* WB[16];
  {
    size_t off = 0;
    WB[0] = wb; off += 256 * 1024;           // seq_init
    for (int i = 1; i < 16; ++i) { WB[i] = wb + off; off += 256 * 256; }
  }

  const dim3 blk(256);
  const dim3 mgrid(313);                // ceil(20000/64) row blocks, full N per block
  const dim3 rgrid((PN + 3) / 4);       // wave-per-row kernels: 4 rows/block
  const dim3 fgridP((EPPI + 255) / 256);
  const dim3 fgridD((EDDI + 255) / 256);
  const dim3 fgridT((EDTI + 255) / 256);

  auto GEMM = [&](const float* X, const __bf16* Wt, const float* bias, float* o, int K, int act) {
    hipLaunchKernelGGL(gemm_mfma, mgrid, blk, 0, stream, X, Wt, bias, o, PN, K, act);
  };
  auto COMB = [&](const float* A, const float* T, const float* dv, const float* gb,
                  const float* L, const float* S, const float* ic,
                  const float* lw, const float* lb, float* o, int n, int act) {
    hipLaunchKernelGGL(combine_ln, rgrid, blk, 0, stream, A, T, dv, gb, L, S, ic, lw, lb, o, n, act);
  };
  auto GGCN = [&](const int* rp, const int* cl, const float* dv, const float* T, float* A) {
    hipLaunchKernelGGL(gather_gcn, rgrid, blk, 0, stream, rp, cl, dv, T, A, PN);
  };
  auto GSUM = [&](const int* rp, const int* cl, const float* T, float* S) {
    hipLaunchKernelGGL(gather_sum, rgrid, blk, 0, stream, rp, cl, T, S, PN);
  };

  // ---- weight conversion (fp32 -> bf16) ----
  {
    WPack p;
    const float* srcs[16] = { seq_init_W, gs1_gcn_W, gs1_lin_W, gs2_gcn_W, gs2_lin_W,
                              dd1_W, dt1_W, dr1_W, pp1_W, td1_W, pr1_W,
                              td2_W, pp2_W, pr2_W, seq_fc_W, skip_fc_W };
    for (int i = 0; i < 16; ++i) { p.src[i] = srcs[i]; p.dst[i] = WB[i]; p.n[i] = (i == 0) ? 256*1024 : 256*256; }
    hipLaunchKernelGGL(convert_weights, dim3(16, 16), blk, 0, stream, p);
  }

  // ---- degrees & counts ----
  hipMemsetAsync(degP, 0, 4 * sizeof(int) * PN, stream);
  hipLaunchKernelGGL(count_kernel, fgridP, blk, 0, stream, ppi + EPPI, degP, EPPI);
  hipLaunchKernelGGL(count_kernel, fgridD, blk, 0, stream, ddi + EDDI, degD, EDDI);
  hipLaunchKernelGGL(count_kernel, fgridT, blk, 0, stream, dti,        cntD, EDTI);
  hipLaunchKernelGGL(count_kernel, fgridT, blk, 0, stream, dti + EDTI, cntP, EDTI);
  hipLaunchKernelGGL(finalize_deg, dim3((PN+255)/256), blk, 0, stream,
                     degP, degD, cntD, cntP, dinvP, dinvD, icD, icP, PN);

  // ---- CSR build (by destination) ----
  hipLaunchKernelGGL(scan_kernel, dim3(1), dim3(1024), 0, stream, degP, rowptrP,  curP,  PN);
  hipLaunchKernelGGL(scan_kernel, dim3(1), dim3(1024), 0, stream, degD, rowptrD,  curD,  DN);
  hipLaunchKernelGGL(scan_kernel, dim3(1), dim3(1024), 0, stream, cntD, rowptrTD, curTD, DN);
  hipLaunchKernelGGL(scan_kernel, dim3(1), dim3(1024), 0, stream, cntP, rowptrTP, curTP, PN);
  hipLaunchKernelGGL(fill_kernel, fgridP, blk, 0, stream, ppi,        ppi + EPPI, curP,  colP,  EPPI);
  hipLaunchKernelGGL(fill_kernel, fgridD, blk, 0, stream, ddi,        ddi + EDDI, curD,  colD,  EDDI);
  hipLaunchKernelGGL(fill_kernel, fgridT, blk, 0, stream, dti + EDTI, dti,        curTD, colTD, EDTI);
  hipLaunchKernelGGL(fill_kernel, fgridT, blk, 0, stream, dti,        dti + EDTI, curTP, colTP, EDTI);

  // ---- P1: x_seq = relu(seq @ seq_init_W^T) -> W0 ----
  GEMM(seq, WB[0], nullptr, W0, SEQK, 1);

  // ---- P2 (gs1): h -> W1 ----
  GEMM(W0, WB[1], nullptr, W1, 256, 0);                           // t
  GGCN(rowptrP, colP, dinvP, W1, W2);
  GEMM(W0, WB[2], nullptr, W3, 256, 0);                           // lin
  COMB(W2, W1, dinvP, gs1_gcn_b, W3, nullptr, nullptr, gs1_ln_w, gs1_ln_b, W1, PN, 1);

  // ---- P3 (gs2): x1 -> W2 ----
  GEMM(W1, WB[3], nullptr, W2, 256, 0);
  GGCN(rowptrP, colP, dinvP, W2, W3);
  GEMM(W1, WB[4], nullptr, W4, 256, 0);
  COMB(W3, W2, dinvP, gs2_gcn_b, W4, nullptr, nullptr, gs2_ln_w, gs2_ln_b, W2, PN, 0);

  // ---- P4d (drug layer 1): d -> W1 ----
  GEMM(drug_emb, WB[5], nullptr, W1, 256, 0);
  GGCN(rowptrD, colD, dinvD, W1, W3);
  GEMM(prot_emb, WB[6], dt1_b, W4, 256, 0);                       // proj_p
  GSUM(rowptrTD, colTD, W4, W5);
  GEMM(drug_emb, WB[7], dr1_b, W4, 256, 0);                       // lin
  COMB(W3, W1, dinvD, dd1_b, W4, W5, icD, nullptr, nullptr, W1, DN, 1);

  // ---- P4p (protein layer 1): p -> W3 ----
  GEMM(prot_emb, WB[8], nullptr, W3, 256, 0);
  GGCN(rowptrP, colP, dinvP, W3, W4);
  GEMM(drug_emb, WB[9], td1_b, W5, 256, 0);                       // proj_d
  GSUM(rowptrTP, colTP, W5, W6);
  GEMM(prot_emb, WB[10], pr1_b, W5, 256, 0);                      // lin
  COMB(W4, W3, dinvP, pp1_b, W5, W6, icP, nullptr, nullptr, W3, PN, 1);

  // ---- P5 (protein layer 2): p2 -> W1 ----
  GEMM(W1, WB[11], td2_b, W4, 256, 0);                            // proj from d (W1)
  GSUM(rowptrTP, colTP, W4, W5);
  GEMM(W3, WB[12], nullptr, W1, 256, 0);                          // t
  GGCN(rowptrP, colP, dinvP, W1, W4);
  GEMM(W3, WB[13], pr2_b, W6, 256, 0);                            // lin
  COMB(W4, W1, dinvP, pp2_b, W6, W5, icP, nullptr, nullptr, W1, PN, 0);

  // ---- P6: fuse precompute ----
  COMB(W0, nullptr, nullptr, nullptr, nullptr, nullptr, nullptr, nullptr, nullptr, W3, PN, 2); // fp = elu(LN(x_seq))
  GEMM(W3, WB[14], nullptr, W4, 256, 2);                          // x_fp
  GEMM(prot_emb, WB[15], nullptr, W5, 256, 0);                    // x_skip

  // ---- P7: pair epilogue ----
  hipLaunchKernelGGL(pair_kernel, dim3((NPAIRN + 3) / 4), blk, 0, stream,
                     W2, W4, W1, W5, idx1, idx2, wR, wI, outp, NPAIRN);
}

// Round 4
// 1527.631 us; speedup vs baseline: 10.6173x; 1.1128x over previous
//
#include <hip/hip_runtime.h>
#include <hip/hip_bf16.h>
#include <math.h>

#define PN 20000
#define DN 20000
#define SEQK 1024
#define EPPI 640000
#define EDDI 640000
#define EDTI 400000
#define NPAIRN 100000

typedef float4 f4;
using bf16x8 = __attribute__((ext_vector_type(8))) __bf16;
using bf16x4 = __attribute__((ext_vector_type(4))) __bf16;
using f32x4v = __attribute__((ext_vector_type(4))) float;

__device__ __forceinline__ f4 ld4(const float* p) { return *reinterpret_cast<const f4*>(p); }
__device__ __forceinline__ void st4(float* p, f4 v) { *reinterpret_cast<f4*>(p) = v; }
__device__ __forceinline__ f4 ldb4(const __bf16* p) {
  bf16x4 v = *reinterpret_cast<const bf16x4*>(p);
  return make_float4((float)v[0], (float)v[1], (float)v[2], (float)v[3]);
}
__device__ __forceinline__ void stb4(__bf16* p, f4 v) {
  bf16x4 o;
  o[0] = (__bf16)v.x; o[1] = (__bf16)v.y; o[2] = (__bf16)v.z; o[3] = (__bf16)v.w;
  *reinterpret_cast<bf16x4*>(p) = o;
}
__device__ __forceinline__ void acc4(f4& a, f4 b) { a.x+=b.x; a.y+=b.y; a.z+=b.z; a.w+=b.w; }
__device__ __forceinline__ void acc4s(f4& a, f4 b, float s) { a.x+=s*b.x; a.y+=s*b.y; a.z+=s*b.z; a.w+=s*b.w; }

// LayerNorm over a 256-wide row held as one float4 per lane across a 64-lane wave.
__device__ __forceinline__ void wave_ln(f4& x) {
  float s  = x.x + x.y + x.z + x.w;
  float ss = x.x*x.x + x.y*x.y + x.z*x.z + x.w*x.w;
#pragma unroll
  for (int o = 32; o; o >>= 1) { s += __shfl_xor(s, o, 64); ss += __shfl_xor(ss, o, 64); }
  float m = s * (1.f/256.f);
  float v = ss * (1.f/256.f) - m*m;
  float r = rsqrtf(v + 1e-5f);
  x.x = (x.x-m)*r; x.y = (x.y-m)*r; x.z = (x.z-m)*r; x.w = (x.w-m)*r;
}

__device__ __forceinline__ bf16x8 cvt8(const float* p) {
  f4 u = ld4(p), v = ld4(p + 4);
  bf16x8 r;
  r[0] = (__bf16)u.x; r[1] = (__bf16)u.y; r[2] = (__bf16)u.z; r[3] = (__bf16)u.w;
  r[4] = (__bf16)v.x; r[5] = (__bf16)v.y; r[6] = (__bf16)v.z; r[7] = (__bf16)v.w;
  return r;
}

// ---------------- weight pre-convert: fp32 -> bf16, 16 weights in one launch ----------------
struct WPack {
  const float* src[16];
  __bf16* dst[16];
  int n[16];
};

__global__ __launch_bounds__(256) void convert_weights(WPack p) {
  const int wi = blockIdx.y;
  const int n = p.n[wi];
  const float* s = p.src[wi];
  __bf16* d = p.dst[wi];
  for (int i = (blockIdx.x * 256 + threadIdx.x) * 4; i < n; i += gridDim.x * 256 * 4) {
    f4 v = ld4(s + i);
    ushort4 o;
    o.x = __builtin_bit_cast(unsigned short, (__bf16)v.x);
    o.y = __builtin_bit_cast(unsigned short, (__bf16)v.y);
    o.z = __builtin_bit_cast(unsigned short, (__bf16)v.z);
    o.w = __builtin_bit_cast(unsigned short, (__bf16)v.w);
    *reinterpret_cast<ushort4*>(d + i) = o;
  }
}

// ---------------- MFMA GEMM: out[M,256] = X[M,K] @ Wt[256,K]^T (+bias)(+act) ----
// X read from Xb (bf16) if non-null, else from Xf (fp32, converted in-kernel).
// Writes fp32 out (outf) and/or bf16 out (outb) — either may be null.
// Block: 256 thr = 4 waves; wave (w>>1, w&1) owns 32 rows x 128 cols. Grid: ceil(M/64).
__global__ __launch_bounds__(256) void gemm_mfma(
    const float* __restrict__ Xf, const __bf16* __restrict__ Xb,
    const __bf16* __restrict__ Wt, const float* __restrict__ bias,
    float* __restrict__ outf, __bf16* __restrict__ outb,
    int M, int K, int act)
{
  const int tid = threadIdx.x;
  const int lane = tid & 63;
  const int w = tid >> 6;
  const int wr = (w >> 1) * 32;
  const int wc = (w & 1) * 128;
  const int r0 = blockIdx.x * 64 + wr;
  const int l15 = lane & 15;
  const int lk = (lane >> 4) * 8;

  f32x4v acc[2][8];
#pragma unroll
  for (int m = 0; m < 2; ++m)
#pragma unroll
    for (int n = 0; n < 8; ++n) { acc[m][n][0]=0.f; acc[m][n][1]=0.f; acc[m][n][2]=0.f; acc[m][n][3]=0.f; }

  int ra = r0 + l15;      if (ra > M - 1) ra = M - 1;
  int rb = r0 + 16 + l15; if (rb > M - 1) rb = M - 1;
  const float*  xfa = Xf ? Xf + (size_t)ra * K + lk : nullptr;
  const float*  xfb = Xf ? Xf + (size_t)rb * K + lk : nullptr;
  const __bf16* xba = Xb ? Xb + (size_t)ra * K + lk : nullptr;
  const __bf16* xbb = Xb ? Xb + (size_t)rb * K + lk : nullptr;
  const __bf16* wp = Wt + (size_t)(wc + l15) * K + lk;

  for (int k0 = 0; k0 < K; k0 += 32) {
    bf16x8 a0, a1;
    if (Xb) {
      a0 = *reinterpret_cast<const bf16x8*>(xba + k0);
      a1 = *reinterpret_cast<const bf16x8*>(xbb + k0);
    } else {
      a0 = cvt8(xfa + k0);
      a1 = cvt8(xfb + k0);
    }
#pragma unroll
    for (int n = 0; n < 8; ++n) {
      bf16x8 b = *reinterpret_cast<const bf16x8*>(wp + (size_t)n * 16 * K + k0);
      acc[0][n] = __builtin_amdgcn_mfma_f32_16x16x32_bf16(a0, b, acc[0][n], 0, 0, 0);
      acc[1][n] = __builtin_amdgcn_mfma_f32_16x16x32_bf16(a1, b, acc[1][n], 0, 0, 0);
    }
  }

  const int rowbase = r0 + (lane >> 4) * 4;
#pragma unroll
  for (int m = 0; m < 2; ++m) {
#pragma unroll
    for (int i = 0; i < 4; ++i) {
      int row = rowbase + m * 16 + i;
      if (row >= M) continue;
      size_t rb0 = (size_t)row * 256 + wc + l15;
#pragma unroll
      for (int n = 0; n < 8; ++n) {
        float v = acc[m][n][i];
        if (bias) v += bias[wc + n * 16 + l15];
        if (act == 1) v = fmaxf(v, 0.f);
        else if (act == 2) v = v > 0.f ? v : (expf(v) - 1.f);
        if (outf) outf[rb0 + n * 16] = v;
        if (outb) outb[rb0 + n * 16] = (__bf16)v;
      }
    }
  }
}

// ---------------- degree / count ----------------
__global__ __launch_bounds__(256) void count_kernel(const int* __restrict__ idx, int* __restrict__ cnt, int n) {
  int i = blockIdx.x * 256 + threadIdx.x;
  if (i < n) atomicAdd(&cnt[idx[i]], 1);
}

__global__ __launch_bounds__(256) void finalize_deg(
    const int* __restrict__ degP, const int* __restrict__ degD,
    const int* __restrict__ cntD, const int* __restrict__ cntP,
    float* __restrict__ dinvP, float* __restrict__ dinvD,
    float* __restrict__ icD, float* __restrict__ icP, int n)
{
  int i = blockIdx.x * 256 + threadIdx.x;
  if (i < n) {
    dinvP[i] = rsqrtf((float)degP[i] + 1.f);  // +1 = self loop
    dinvD[i] = rsqrtf((float)degD[i] + 1.f);
    icD[i] = 1.f / fmaxf((float)cntD[i], 1.f);
    icP[i] = 1.f / fmaxf((float)cntP[i], 1.f);
  }
}

// ---------------- single-block exclusive scan: rowptr[0..n] from cnt[0..n-1]; cur = rowptr copy ----
__global__ __launch_bounds__(1024) void scan_kernel(
    const int* __restrict__ cnt, int* __restrict__ rowptr, int* __restrict__ cur, int n)
{
  __shared__ int sums[1024];
  const int t = threadIdx.x;
  const int chunk = (n + 1023) / 1024;
  const int b = t * chunk;
  const int e = min(b + chunk, n);
  int s = 0;
  for (int i = b; i < e; ++i) s += cnt[i];
  sums[t] = s;
  __syncthreads();
  for (int o = 1; o < 1024; o <<= 1) {
    int u = (t >= o) ? sums[t - o] : 0;
    __syncthreads();
    sums[t] += u;
    __syncthreads();
  }
  int run = sums[t] - s;   // exclusive offset
  for (int i = b; i < e; ++i) { rowptr[i] = run; cur[i] = run; run += cnt[i]; }
  if (t == 1023) rowptr[n] = sums[1023];
}

// ---------------- CSR fill: col[pos] = src, pos allocated by atomic cursor on dst ----------------
__global__ __launch_bounds__(256) void fill_kernel(
    const int* __restrict__ src, const int* __restrict__ dst,
    int* __restrict__ cur, int* __restrict__ col, int nE)
{
  int e = blockIdx.x * 256 + threadIdx.x;
  if (e < nE) {
    int d = dst[e];
    int pos = atomicAdd(&cur[d], 1);
    col[pos] = src[e];
  }
}

// ---------------- GCN gather: A[d] = sum_j dinv[col[j]]*dinv[d] * T[col[j]]  (T bf16, A fp32) ----
__global__ __launch_bounds__(256) void gather_gcn(
    const int* __restrict__ rowptr, const int* __restrict__ col,
    const float* __restrict__ dinv, const __bf16* __restrict__ T,
    float* __restrict__ A, int n)
{
  int row = (blockIdx.x * blockDim.x + threadIdx.x) >> 6;
  if (row >= n) return;
  int lane = threadIdx.x & 63;
  int beg = rowptr[row], end = rowptr[row + 1];
  float dd = dinv[row];
  f4 a = make_float4(0.f, 0.f, 0.f, 0.f);
  int j = beg;
  for (; j + 1 < end; j += 2) {
    int s0 = col[j], s1 = col[j + 1];
    float n0 = dd * dinv[s0], n1 = dd * dinv[s1];
    f4 t0 = ldb4(T + (size_t)s0 * 256 + lane * 4);
    f4 t1 = ldb4(T + (size_t)s1 * 256 + lane * 4);
    acc4s(a, t0, n0);
    acc4s(a, t1, n1);
  }
  if (j < end) {
    int s0 = col[j];
    acc4s(a, ldb4(T + (size_t)s0 * 256 + lane * 4), dd * dinv[s0]);
  }
  st4(A + (size_t)row * 256 + lane * 4, a);
}

// ---------------- plain gather-sum (for scatter_mean numerator), T bf16 -> S fp32 ----------------
__global__ __launch_bounds__(256) void gather_sum(
    const int* __restrict__ rowptr, const int* __restrict__ col,
    const __bf16* __restrict__ T, float* __restrict__ S, int n)
{
  int row = (blockIdx.x * blockDim.x + threadIdx.x) >> 6;
  if (row >= n) return;
  int lane = threadIdx.x & 63;
  int beg = rowptr[row], end = rowptr[row + 1];
  f4 a = make_float4(0.f, 0.f, 0.f, 0.f);
  int j = beg;
  for (; j + 1 < end; j += 2) {
    int s0 = col[j], s1 = col[j + 1];
    f4 t0 = ldb4(T + (size_t)s0 * 256 + lane * 4);
    f4 t1 = ldb4(T + (size_t)s1 * 256 + lane * 4);
    acc4(a, t0);
    acc4(a, t1);
  }
  if (j < end) acc4(a, ldb4(T + (size_t)col[j] * 256 + lane * 4));
  st4(S + (size_t)row * 256 + lane * 4, a);
}

// ---------------- combine: out(bf16) = act( LN( A + dinv^2*T + gb + L + ic*S ) [*lw+lb] ) ----------
__global__ __launch_bounds__(256) void combine_ln(
    const float* __restrict__ A, const float* __restrict__ T, const float* __restrict__ dinv,
    const float* __restrict__ gb, const float* __restrict__ L,
    const float* __restrict__ S, const float* __restrict__ ic,
    const float* __restrict__ lw, const float* __restrict__ lb,
    __bf16* __restrict__ out, int n, int act)
{
  int row = (blockIdx.x * blockDim.x + threadIdx.x) >> 6;
  if (row >= n) return;
  int lane = threadIdx.x & 63;
  size_t base = (size_t)row * 256 + lane*4;
  f4 x = make_float4(0.f,0.f,0.f,0.f);
  if (A) acc4(x, ld4(A + base));
  if (T) { float dv = dinv[row]; acc4s(x, ld4(T + base), dv*dv); }
  if (gb) acc4(x, ld4(gb + lane*4));
  if (L) acc4(x, ld4(L + base));
  if (S) acc4s(x, ld4(S + base), ic[row]);
  wave_ln(x);
  if (lw) {
    f4 w = ld4(lw + lane*4), b = ld4(lb + lane*4);
    x.x = x.x*w.x + b.x; x.y = x.y*w.y + b.y; x.z = x.z*w.z + b.z; x.w = x.w*w.w + b.w;
  }
  if (act == 1) {
    x.x = fmaxf(x.x, 0.f); x.y = fmaxf(x.y, 0.f); x.z = fmaxf(x.z, 0.f); x.w = fmaxf(x.w, 0.f);
  } else if (act == 2) {
    x.x = x.x > 0.f ? x.x : expf(x.x)-1.f;
    x.y = x.y > 0.f ? x.y : expf(x.y)-1.f;
    x.z = x.z > 0.f ? x.z : expf(x.z)-1.f;
    x.w = x.w > 0.f ? x.w : expf(x.w)-1.f;
  }
  stb4(out + base, x);
}

// ---------------- pair epilogue: complex fuse, one wave per pair; tables bf16 ----------------
__global__ __launch_bounds__(256) void pair_kernel(
    const __bf16* __restrict__ x1, const __bf16* __restrict__ xfp,
    const __bf16* __restrict__ p2, const __bf16* __restrict__ xskip,
    const int* __restrict__ idx1, const int* __restrict__ idx2,
    const float* __restrict__ wR, const float* __restrict__ wI,
    float* __restrict__ out, int npair)
{
  int wid = (blockIdx.x * blockDim.x + threadIdx.x) >> 6;
  if (wid >= npair) return;
  int lane = threadIdx.x & 63;
  int f = lane * 4;
  size_t o1 = (size_t)idx1[wid] * 256 + f;
  size_t o2 = (size_t)idx2[wid] * 256 + f;

  f4 R1 = ldb4(x1 + o1);    acc4(R1, ldb4(xfp + o2));   wave_ln(R1);
  f4 I1 = ldb4(p2 + o1);    acc4(I1, ldb4(xskip + o2)); wave_ln(I1);
  f4 R2 = ldb4(xskip + o1); acc4(R2, ldb4(p2 + o2));    wave_ln(R2);
  f4 I2 = ldb4(xfp + o1);   acc4(I2, ldb4(x1 + o2));    wave_ln(I2);

  f4 R, I;
  R.x = R1.x*R2.x - I1.x*I2.x;  I.x = R1.x*I2.x + I1.x*R2.x;
  R.y = R1.y*R2.y - I1.y*I2.y;  I.y = R1.y*I2.y + I1.y*R2.y;
  R.z = R1.z*R2.z - I1.z*I2.z;  I.z = R1.z*I2.z + I1.z*R2.z;
  R.w = R1.w*R2.w - I1.w*I2.w;  I.w = R1.w*I2.w + I1.w*R2.w;
  wave_ln(R); wave_ln(I);

  f4 wr = ld4(wR + f), wi = ld4(wI + f);
  float r_ = R.x*wr.x + I.x*wi.x + R.y*wr.y + I.y*wi.y
           + R.z*wr.z + I.z*wi.z + R.w*wr.w + I.w*wi.w;
  float i_ = I.x*wr.x - R.x*wi.x + I.y*wr.y - R.y*wi.y
           + I.z*wr.z - R.z*wi.z + I.w*wr.w - R.w*wi.w;
  float t = r_ + i_;
#pragma unroll
  for (int o = 32; o; o >>= 1) t += __shfl_xor(t, o, 64);
  if (lane == 0) out[wid] = 1.f / (1.f + expf(-t));
}

extern "C" void kernel_launch(void* const* d_in, const int* in_sizes, int n_in,
                              void* d_out, int out_size, void* d_ws, size_t ws_size,
                              hipStream_t stream) {
  (void)in_sizes; (void)n_in; (void)out_size; (void)ws_size;
  const float* seq        = (const float*)d_in[0];
  const int*   ppi        = (const int*)d_in[1];
  const int*   ddi        = (const int*)d_in[2];
  const int*   dti        = (const int*)d_in[3];
  const int*   idx1       = (const int*)d_in[4];
  const int*   idx2       = (const int*)d_in[5];
  const float* seq_init_W = (const float*)d_in[6];
  const float* gs1_gcn_W  = (const float*)d_in[7];
  const float* gs1_gcn_b  = (const float*)d_in[8];
  const float* gs1_lin_W  = (const float*)d_in[9];
  const float* gs1_ln_w   = (const float*)d_in[10];
  const float* gs1_ln_b   = (const float*)d_in[11];
  const float* gs2_gcn_W  = (const float*)d_in[12];
  const float* gs2_gcn_b  = (const float*)d_in[13];
  const float* gs2_lin_W  = (const float*)d_in[14];
  const float* gs2_ln_w   = (const float*)d_in[15];
  const float* gs2_ln_b   = (const float*)d_in[16];
  const float* drug_emb   = (const float*)d_in[17];
  const float* prot_emb   = (const float*)d_in[18];
  const float* pp1_W = (const float*)d_in[19]; const float* pp1_b = (const float*)d_in[20];
  const float* td1_W = (const float*)d_in[21]; const float* td1_b = (const float*)d_in[22];
  const float* pr1_W = (const float*)d_in[23]; const float* pr1_b = (const float*)d_in[24];
  const float* dd1_W = (const float*)d_in[25]; const float* dd1_b = (const float*)d_in[26];
  const float* dt1_W = (const float*)d_in[27]; const float* dt1_b = (const float*)d_in[28];
  const float* dr1_W = (const float*)d_in[29]; const float* dr1_b = (const float*)d_in[30];
  const float* pp2_W = (const float*)d_in[31]; const float* pp2_b = (const float*)d_in[32];
  const float* td2_W = (const float*)d_in[33]; const float* td2_b = (const float*)d_in[34];
  const float* pr2_W = (const float*)d_in[35]; const float* pr2_b = (const float*)d_in[36];
  // d_in[37..42]: dd2/dt2/dr2 — dead code in ASC path
  const float* seq_fc_W  = (const float*)d_in[43];
  const float* skip_fc_W = (const float*)d_in[44];
  const float* wR = (const float*)d_in[45];
  const float* wI = (const float*)d_in[46];
  float* outp = (float*)d_out;

  float* ws = (float*)d_ws;
  const size_t NB = (size_t)PN * 256;
  // fp32 pool: F0..F4
  float* F0 = ws + 0*NB;  // x_seq (fp32, for P6 LN input)
  float* F1 = ws + 1*NB;  // t (self-loop input to combine)
  float* F2 = ws + 2*NB;  // gather_gcn out A
  float* F3 = ws + 3*NB;  // lin out L
  float* F4 = ws + 4*NB;  // gather_sum out S
  int*   ib   = (int*)(ws + 5*NB);
  int*   degP = ib;             // counts, contiguous block of 4*PN for one memset
  int*   degD = degP + PN;
  int*   cntD = degD + DN;
  int*   cntP = cntD + DN;
  float* dinvP = (float*)(cntP + PN);
  float* dinvD = dinvP + PN;
  float* icD   = dinvD + DN;
  float* icP   = icD + DN;
  int* rowptrP  = (int*)(icP + PN);
  int* rowptrD  = rowptrP  + PN + 1;
  int* rowptrTD = rowptrD  + DN + 1;
  int* rowptrTP = rowptrTD + DN + 1;
  int* curP  = rowptrTP + PN + 1;
  int* curD  = curP + PN;
  int* curTD = curD + DN;
  int* curTP = curTD + DN;
  int* colP  = curTP + PN;      // EPPI
  int* colD  = colP + EPPI;     // EDDI
  int* colTD = colD + EDDI;     // EDTI
  int* colTP = colTD + EDTI;    // EDTI

  // bf16 weight buffers (aligned up to 64B)
  unsigned long long waddr = (unsigned long long)(colTP + EDTI);
  waddr = (waddr + 63ULL) & ~63ULL;
  __bf16* wb = (__bf16*)waddr;
  __bf16* WB[16];
  {
    size_t off = 0;
    WB[0] = wb; off += 256 * 1024;           // seq_init
    for (int i = 1; i < 16; ++i) { WB[i] = wb + off; off += 256 * 256; }
  }
  // bf16 intermediate pool: B0..B5 (each NB bf16)
  __bf16* bp = wb + (256 * 1024 + 15 * 256 * 256);
  __bf16* B0 = bp + 0*NB;   // x_seq bf16 -> later x_fp
  __bf16* B1 = bp + 1*NB;   // t bf16 (gather input) -> later p2
  __bf16* B2 = bp + 2*NB;   // h -> d
  __bf16* B3 = bp + 3*NB;   // x1 (live to P7)
  __bf16* B4 = bp + 4*NB;   // proj -> fp
  __bf16* B5 = bp + 5*NB;   // p -> x_skip

  const dim3 blk(256);
  const dim3 mgrid(313);                // ceil(20000/64) row blocks, full N per block
  const dim3 rgrid((PN + 3) / 4);       // wave-per-row kernels: 4 rows/block
  const dim3 fgridP((EPPI + 255) / 256);
  const dim3 fgridD((EDDI + 255) / 256);
  const dim3 fgridT((EDTI + 255) / 256);

  auto GEMM = [&](const float* Xf, const __bf16* Xb, const __bf16* Wt, const float* bias,
                  float* outf, __bf16* outb, int K, int act) {
    hipLaunchKernelGGL(gemm_mfma, mgrid, blk, 0, stream, Xf, Xb, Wt, bias, outf, outb, PN, K, act);
  };
  auto COMB = [&](const float* A, const float* T, const float* dv, const float* gb,
                  const float* L, const float* S, const float* ic,
                  const float* lw, const float* lb, __bf16* o, int n, int act) {
    hipLaunchKernelGGL(combine_ln, rgrid, blk, 0, stream, A, T, dv, gb, L, S, ic, lw, lb, o, n, act);
  };
  auto GGCN = [&](const int* rp, const int* cl, const float* dv, const __bf16* T, float* A) {
    hipLaunchKernelGGL(gather_gcn, rgrid, blk, 0, stream, rp, cl, dv, T, A, PN);
  };
  auto GSUM = [&](const int* rp, const int* cl, const __bf16* T, float* S) {
    hipLaunchKernelGGL(gather_sum, rgrid, blk, 0, stream, rp, cl, T, S, PN);
  };

  // ---- weight conversion (fp32 -> bf16) ----
  {
    WPack p;
    const float* srcs[16] = { seq_init_W, gs1_gcn_W, gs1_lin_W, gs2_gcn_W, gs2_lin_W,
                              dd1_W, dt1_W, dr1_W, pp1_W, td1_W, pr1_W,
                              td2_W, pp2_W, pr2_W, seq_fc_W, skip_fc_W };
    for (int i = 0; i < 16; ++i) { p.src[i] = srcs[i]; p.dst[i] = WB[i]; p.n[i] = (i == 0) ? 256*1024 : 256*256; }
    hipLaunchKernelGGL(convert_weights, dim3(16, 16), blk, 0, stream, p);
  }

  // ---- degrees & counts ----
  hipMemsetAsync(degP, 0, 4 * sizeof(int) * PN, stream);
  hipLaunchKernelGGL(count_kernel, fgridP, blk, 0, stream, ppi + EPPI, degP, EPPI);
  hipLaunchKernelGGL(count_kernel, fgridD, blk, 0, stream, ddi + EDDI, degD, EDDI);
  hipLaunchKernelGGL(count_kernel, fgridT, blk, 0, stream, dti,        cntD, EDTI);
  hipLaunchKernelGGL(count_kernel, fgridT, blk, 0, stream, dti + EDTI, cntP, EDTI);
  hipLaunchKernelGGL(finalize_deg, dim3((PN+255)/256), blk, 0, stream,
                     degP, degD, cntD, cntP, dinvP, dinvD, icD, icP, PN);

  // ---- CSR build (by destination) ----
  hipLaunchKernelGGL(scan_kernel, dim3(1), dim3(1024), 0, stream, degP, rowptrP,  curP,  PN);
  hipLaunchKernelGGL(scan_kernel, dim3(1), dim3(1024), 0, stream, degD, rowptrD,  curD,  DN);
  hipLaunchKernelGGL(scan_kernel, dim3(1), dim3(1024), 0, stream, cntD, rowptrTD, curTD, DN);
  hipLaunchKernelGGL(scan_kernel, dim3(1), dim3(1024), 0, stream, cntP, rowptrTP, curTP, PN);
  hipLaunchKernelGGL(fill_kernel, fgridP, blk, 0, stream, ppi,        ppi + EPPI, curP,  colP,  EPPI);
  hipLaunchKernelGGL(fill_kernel, fgridD, blk, 0, stream, ddi,        ddi + EDDI, curD,  colD,  EDDI);
  hipLaunchKernelGGL(fill_kernel, fgridT, blk, 0, stream, dti + EDTI, dti,        curTD, colTD, EDTI);
  hipLaunchKernelGGL(fill_kernel, fgridT, blk, 0, stream, dti,        dti + EDTI, curTP, colTP, EDTI);

  // ---- P1: x_seq = relu(seq @ seq_init_W^T) -> F0 (fp32) + B0 (bf16) ----
  GEMM(seq, nullptr, WB[0], nullptr, F0, B0, SEQK, 1);

  // ---- P2 (gs1): h -> B2 ----
  GEMM(nullptr, B0, WB[1], nullptr, F1, B1, 256, 0);              // t
  GGCN(rowptrP, colP, dinvP, B1, F2);
  GEMM(nullptr, B0, WB[2], nullptr, F3, nullptr, 256, 0);         // lin
  COMB(F2, F1, dinvP, gs1_gcn_b, F3, nullptr, nullptr, gs1_ln_w, gs1_ln_b, B2, PN, 1);

  // ---- P3 (gs2): x1 -> B3 ----
  GEMM(nullptr, B2, WB[3], nullptr, F1, B1, 256, 0);              // t
  GGCN(rowptrP, colP, dinvP, B1, F2);
  GEMM(nullptr, B2, WB[4], nullptr, F3, nullptr, 256, 0);         // lin
  COMB(F2, F1, dinvP, gs2_gcn_b, F3, nullptr, nullptr, gs2_ln_w, gs2_ln_b, B3, PN, 0);

  // ---- P4d (drug layer 1): d -> B2 ----
  GEMM(drug_emb, nullptr, WB[5], nullptr, F1, B1, 256, 0);        // t (dd1)
  hipLaunchKernelGGL(gather_gcn, rgrid, blk, 0, stream, rowptrD, colD, dinvD, B1, F2, DN);
  GEMM(prot_emb, nullptr, WB[6], dt1_b, nullptr, B4, 256, 0);     // proj_p (bf16 only)
  GSUM(rowptrTD, colTD, B4, F4);
  GEMM(drug_emb, nullptr, WB[7], dr1_b, F3, nullptr, 256, 0);     // lin (dr1)
  COMB(F2, F1, dinvD, dd1_b, F3, F4, icD, nullptr, nullptr, B2, DN, 1);

  // ---- P4p (protein layer 1): p -> B5 ----
  GEMM(prot_emb, nullptr, WB[8], nullptr, F1, B1, 256, 0);        // t (pp1)
  GGCN(rowptrP, colP, dinvP, B1, F2);
  GEMM(drug_emb, nullptr, WB[9], td1_b, nullptr, B4, 256, 0);     // proj_d
  GSUM(rowptrTP, colTP, B4, F4);
  GEMM(prot_emb, nullptr, WB[10], pr1_b, F3, nullptr, 256, 0);    // lin (pr1)
  COMB(F2, F1, dinvP, pp1_b, F3, F4, icP, nullptr, nullptr, B5, PN, 1);

  // ---- P5 (protein layer 2): p2 -> B1 ----
  GEMM(nullptr, B2, WB[11], td2_b, nullptr, B4, 256, 0);          // proj (td2) from d
  GSUM(rowptrTP, colTP, B4, F4);
  GEMM(nullptr, B5, WB[12], nullptr, F1, B1, 256, 0);             // t (pp2) from p
  GGCN(rowptrP, colP, dinvP, B1, F2);
  GEMM(nullptr, B5, WB[13], pr2_b, F3, nullptr, 256, 0);          // lin (pr2)
  COMB(F2, F1, dinvP, pp2_b, F3, F4, icP, nullptr, nullptr, B1, PN, 0);

  // ---- P6: fuse precompute ----
  COMB(F0, nullptr, nullptr, nullptr, nullptr, nullptr, nullptr, nullptr, nullptr, B4, PN, 2); // fp = elu(LN(x_seq))
  GEMM(nullptr, B4, WB[14], nullptr, nullptr, B0, 256, 2);        // x_fp -> B0
  GEMM(prot_emb, nullptr, WB[15], nullptr, nullptr, B5, 256, 0);  // x_skip -> B5

  // ---- P7: pair epilogue ----
  hipLaunchKernelGGL(pair_kernel, dim3((NPAIRN + 3) / 4), blk, 0, stream,
                     B3, B0, B1, B5, idx1, idx2, wR, wI, outp, NPAIRN);
}

// Round 5
// 1132.373 us; speedup vs baseline: 14.3233x; 1.3491x over previous
//
#include <hip/hip_runtime.h>
#include <hip/hip_bf16.h>
#include <math.h>

#define PN 20000
#define DN 20000
#define SEQK 1024
#define EPPI 640000
#define EDDI 640000
#define EDTI 400000
#define NPAIRN 100000

typedef float4 f4;
using bf16x8 = __attribute__((ext_vector_type(8))) __bf16;
using bf16x4 = __attribute__((ext_vector_type(4))) __bf16;
using f32x4v = __attribute__((ext_vector_type(4))) float;

__device__ __forceinline__ f4 ld4(const float* p) { return *reinterpret_cast<const f4*>(p); }
__device__ __forceinline__ void st4(float* p, f4 v) { *reinterpret_cast<f4*>(p) = v; }
__device__ __forceinline__ f4 ldb4(const __bf16* p) {
  bf16x4 v = *reinterpret_cast<const bf16x4*>(p);
  return make_float4((float)v[0], (float)v[1], (float)v[2], (float)v[3]);
}
__device__ __forceinline__ void stb4(__bf16* p, f4 v) {
  bf16x4 o;
  o[0] = (__bf16)v.x; o[1] = (__bf16)v.y; o[2] = (__bf16)v.z; o[3] = (__bf16)v.w;
  *reinterpret_cast<bf16x4*>(p) = o;
}
__device__ __forceinline__ void acc4(f4& a, f4 b) { a.x+=b.x; a.y+=b.y; a.z+=b.z; a.w+=b.w; }
__device__ __forceinline__ void acc4s(f4& a, f4 b, float s) { a.x+=s*b.x; a.y+=s*b.y; a.z+=s*b.z; a.w+=s*b.w; }

// LayerNorm over a 256-wide row held as one float4 per lane across a 64-lane wave.
__device__ __forceinline__ void wave_ln(f4& x) {
  float s  = x.x + x.y + x.z + x.w;
  float ss = x.x*x.x + x.y*x.y + x.z*x.z + x.w*x.w;
#pragma unroll
  for (int o = 32; o; o >>= 1) { s += __shfl_xor(s, o, 64); ss += __shfl_xor(ss, o, 64); }
  float m = s * (1.f/256.f);
  float v = ss * (1.f/256.f) - m*m;
  float r = rsqrtf(v + 1e-5f);
  x.x = (x.x-m)*r; x.y = (x.y-m)*r; x.z = (x.z-m)*r; x.w = (x.w-m)*r;
}

// ---------------- fp32 -> bf16 converters ----------------
struct WPack { const float* src[16]; __bf16* dst[16]; int n[16]; };

__global__ __launch_bounds__(256) void convert_weights(WPack p) {
  const int wi = blockIdx.y;
  const int n = p.n[wi];
  const float* s = p.src[wi];
  __bf16* d = p.dst[wi];
  for (int i = (blockIdx.x * 256 + threadIdx.x) * 4; i < n; i += gridDim.x * 256 * 4) {
    f4 v = ld4(s + i);
    stb4(d + i, v);
  }
}

struct EPack { const float* src[3]; __bf16* dst[3]; int n[3]; };

__global__ __launch_bounds__(256) void convert_emb(EPack p) {
  const int wi = blockIdx.y;
  const int n = p.n[wi];
  const float* s = p.src[wi];
  __bf16* d = p.dst[wi];
  for (int i = (blockIdx.x * 256 + threadIdx.x) * 4; i < n; i += gridDim.x * 256 * 4) {
    f4 v = ld4(s + i);
    stb4(d + i, v);
  }
}

// ---------------- MFMA GEMM: out[M,*] = X[M,K](bf16) @ Wt[N,K](bf16)^T (+bias)(+act) ------
// Block: 64 rows x 64 cols, 4 waves; wave (w>>1, w&1) owns 32x32. Grid: (ceil(M/64), N/64).
// Stores at row*ostride + col (ostride 256 or 512). outf/outb optional.
__global__ __launch_bounds__(256) void gemm_mfma(
    const __bf16* __restrict__ X, const __bf16* __restrict__ Wt,
    const float* __restrict__ bias,
    float* __restrict__ outf, __bf16* __restrict__ outb,
    int M, int K, int ostride, int act)
{
  const int tid = threadIdx.x;
  const int lane = tid & 63;
  const int w = tid >> 6;
  const int r0 = blockIdx.x * 64 + (w >> 1) * 32;
  const int c0 = blockIdx.y * 64 + (w & 1) * 32;
  const int l15 = lane & 15;
  const int lk = (lane >> 4) * 8;

  f32x4v acc[2][2];
#pragma unroll
  for (int m = 0; m < 2; ++m)
#pragma unroll
    for (int n = 0; n < 2; ++n) { acc[m][n][0]=0.f; acc[m][n][1]=0.f; acc[m][n][2]=0.f; acc[m][n][3]=0.f; }

  int ra = min(r0 + l15, M - 1);
  int rb = min(r0 + 16 + l15, M - 1);
  const __bf16* xa = X + (size_t)ra * K + lk;
  const __bf16* xb = X + (size_t)rb * K + lk;
  const __bf16* wa = Wt + (size_t)(c0 + l15) * K + lk;
  const __bf16* wc = Wt + (size_t)(c0 + 16 + l15) * K + lk;

  for (int k0 = 0; k0 < K; k0 += 32) {
    bf16x8 a0 = *reinterpret_cast<const bf16x8*>(xa + k0);
    bf16x8 a1 = *reinterpret_cast<const bf16x8*>(xb + k0);
    bf16x8 b0 = *reinterpret_cast<const bf16x8*>(wa + k0);
    bf16x8 b1 = *reinterpret_cast<const bf16x8*>(wc + k0);
    acc[0][0] = __builtin_amdgcn_mfma_f32_16x16x32_bf16(a0, b0, acc[0][0], 0, 0, 0);
    acc[0][1] = __builtin_amdgcn_mfma_f32_16x16x32_bf16(a0, b1, acc[0][1], 0, 0, 0);
    acc[1][0] = __builtin_amdgcn_mfma_f32_16x16x32_bf16(a1, b0, acc[1][0], 0, 0, 0);
    acc[1][1] = __builtin_amdgcn_mfma_f32_16x16x32_bf16(a1, b1, acc[1][1], 0, 0, 0);
  }

  const int rowbase = r0 + (lane >> 4) * 4;
#pragma unroll
  for (int m = 0; m < 2; ++m) {
#pragma unroll
    for (int i = 0; i < 4; ++i) {
      int row = rowbase + m * 16 + i;
      if (row >= M) continue;
#pragma unroll
      for (int n2 = 0; n2 < 2; ++n2) {
        int col = c0 + n2 * 16 + l15;
        float v = acc[m][n2][i];
        if (bias) v += bias[col];
        if (act == 1) v = fmaxf(v, 0.f);
        else if (act == 2) v = v > 0.f ? v : (expf(v) - 1.f);
        size_t idx = (size_t)row * ostride + col;
        if (outf) outf[idx] = v;
        if (outb) outb[idx] = (__bf16)v;
      }
    }
  }
}

// ---------------- CSR build: counts (grid.y=4), finalize, scans (grid.y=4), fills (grid.y=4) ----
struct C4 { const int* idx[4]; int* cnt[4]; int n[4]; };
__global__ __launch_bounds__(256) void count4(C4 g) {
  int y = blockIdx.y;
  int i = blockIdx.x * 256 + threadIdx.x;
  if (i < g.n[y]) atomicAdd(&g.cnt[y][g.idx[y][i]], 1);
}

__global__ __launch_bounds__(256) void finalize_deg(
    const int* __restrict__ degP, const int* __restrict__ degD,
    const int* __restrict__ cntD, const int* __restrict__ cntP,
    float* __restrict__ dinvP, float* __restrict__ dinvD,
    float* __restrict__ icD, float* __restrict__ icP, int n)
{
  int i = blockIdx.x * 256 + threadIdx.x;
  if (i < n) {
    dinvP[i] = rsqrtf((float)degP[i] + 1.f);  // +1 = self loop
    dinvD[i] = rsqrtf((float)degD[i] + 1.f);
    icD[i] = 1.f / fmaxf((float)cntD[i], 1.f);
    icP[i] = 1.f / fmaxf((float)cntP[i], 1.f);
  }
}

struct S4 { const int* cnt[4]; int* rowptr[4]; int* cur[4]; int n[4]; };
__global__ __launch_bounds__(1024) void scan4(S4 g) {
  __shared__ int sums[1024];
  const int y = blockIdx.y;
  const int n = g.n[y];
  const int* cnt = g.cnt[y];
  int* rowptr = g.rowptr[y];
  int* cur = g.cur[y];
  const int t = threadIdx.x;
  const int chunk = (n + 1023) / 1024;
  const int b = t * chunk;
  const int e = min(b + chunk, n);
  int s = 0;
  for (int i = b; i < e; ++i) s += cnt[i];
  sums[t] = s;
  __syncthreads();
  for (int o = 1; o < 1024; o <<= 1) {
    int u = (t >= o) ? sums[t - o] : 0;
    __syncthreads();
    sums[t] += u;
    __syncthreads();
  }
  int run = sums[t] - s;   // exclusive offset
  for (int i = b; i < e; ++i) { rowptr[i] = run; cur[i] = run; run += cnt[i]; }
  if (t == 1023) rowptr[n] = sums[1023];
}

struct FI4 { const int* src[4]; const int* dst[4]; int* cur[4]; int* col[4]; int n[4]; };
__global__ __launch_bounds__(256) void fill4(FI4 g) {
  int y = blockIdx.y;
  int i = blockIdx.x * 256 + threadIdx.x;
  if (i < g.n[y]) {
    int d = g.dst[y][i];
    int pos = atomicAdd(&g.cur[y][d], 1);
    g.col[y][pos] = g.src[y][i];
  }
}

// ---------------- fused GCN stage: out = act( LN( self + gather + gb + linb + L + ic*sum(Pt) )[*lw+lb] )
// T/L live in a TL buffer with stride tstride (t at col 0, lin at col 256). Pt stride 256.
__global__ __launch_bounds__(256) void gcn_combine(
    const int* __restrict__ rpG, const int* __restrict__ clG,
    const float* __restrict__ dinv,
    const __bf16* __restrict__ T, int tstride,
    const float* __restrict__ gb, const float* __restrict__ linb,
    const __bf16* __restrict__ L,
    const int* __restrict__ rpS, const int* __restrict__ clS,
    const float* __restrict__ ic, const __bf16* __restrict__ Pt,
    const float* __restrict__ lw, const float* __restrict__ lb,
    __bf16* __restrict__ out, int n, int act)
{
  int row = (blockIdx.x * blockDim.x + threadIdx.x) >> 6;
  if (row >= n) return;
  int lane = threadIdx.x & 63;
  int o = lane * 4;
  float dd = dinv[row];

  f4 x = make_float4(0.f, 0.f, 0.f, 0.f);
  acc4s(x, ldb4(T + (size_t)row * tstride + o), dd * dd);   // self loop

  int beg = rpG[row], end = rpG[row + 1];
  int j = beg;
  for (; j + 3 < end; j += 4) {
    int s0 = clG[j], s1 = clG[j+1], s2 = clG[j+2], s3 = clG[j+3];
    float n0 = dd * dinv[s0], n1 = dd * dinv[s1], n2 = dd * dinv[s2], n3 = dd * dinv[s3];
    f4 t0 = ldb4(T + (size_t)s0 * tstride + o);
    f4 t1 = ldb4(T + (size_t)s1 * tstride + o);
    f4 t2 = ldb4(T + (size_t)s2 * tstride + o);
    f4 t3 = ldb4(T + (size_t)s3 * tstride + o);
    acc4s(x, t0, n0); acc4s(x, t1, n1); acc4s(x, t2, n2); acc4s(x, t3, n3);
  }
  for (; j < end; ++j) {
    int s0 = clG[j];
    acc4s(x, ldb4(T + (size_t)s0 * tstride + o), dd * dinv[s0]);
  }

  if (gb)   acc4(x, ld4(gb + o));
  if (linb) acc4(x, ld4(linb + o));
  if (L)    acc4(x, ldb4(L + (size_t)row * tstride + o));

  if (rpS) {
    f4 s = make_float4(0.f, 0.f, 0.f, 0.f);
    int sb = rpS[row], se = rpS[row + 1];
    int k = sb;
    for (; k + 3 < se; k += 4) {
      int s0 = clS[k], s1 = clS[k+1], s2 = clS[k+2], s3 = clS[k+3];
      f4 t0 = ldb4(Pt + (size_t)s0 * 256 + o);
      f4 t1 = ldb4(Pt + (size_t)s1 * 256 + o);
      f4 t2 = ldb4(Pt + (size_t)s2 * 256 + o);
      f4 t3 = ldb4(Pt + (size_t)s3 * 256 + o);
      acc4(s, t0); acc4(s, t1); acc4(s, t2); acc4(s, t3);
    }
    for (; k < se; ++k) acc4(s, ldb4(Pt + (size_t)clS[k] * 256 + o));
    acc4s(x, s, ic[row]);
  }

  wave_ln(x);
  if (lw) {
    f4 w = ld4(lw + o), b = ld4(lb + o);
    x.x = x.x*w.x + b.x; x.y = x.y*w.y + b.y; x.z = x.z*w.z + b.z; x.w = x.w*w.w + b.w;
  }
  if (act == 1) {
    x.x = fmaxf(x.x, 0.f); x.y = fmaxf(x.y, 0.f); x.z = fmaxf(x.z, 0.f); x.w = fmaxf(x.w, 0.f);
  }
  stb4(out + (size_t)row * 256 + o, x);
}

// ---------------- fp = elu(LN(x_seq)) from fp32 ----------------
__global__ __launch_bounds__(256) void ln_elu(const float* __restrict__ in, __bf16* __restrict__ out, int n) {
  int row = (blockIdx.x * blockDim.x + threadIdx.x) >> 6;
  if (row >= n) return;
  int lane = threadIdx.x & 63;
  int o = lane * 4;
  f4 x = ld4(in + (size_t)row * 256 + o);
  wave_ln(x);
  x.x = x.x > 0.f ? x.x : expf(x.x)-1.f;
  x.y = x.y > 0.f ? x.y : expf(x.y)-1.f;
  x.z = x.z > 0.f ? x.z : expf(x.z)-1.f;
  x.w = x.w > 0.f ? x.w : expf(x.w)-1.f;
  stb4(out + (size_t)row * 256 + o, x);
}

// ---------------- pair epilogue: complex fuse, one wave per pair; tables bf16 ----------------
__global__ __launch_bounds__(256) void pair_kernel(
    const __bf16* __restrict__ x1, const __bf16* __restrict__ xfp,
    const __bf16* __restrict__ p2, const __bf16* __restrict__ xskip,
    const int* __restrict__ idx1, const int* __restrict__ idx2,
    const float* __restrict__ wR, const float* __restrict__ wI,
    float* __restrict__ out, int npair)
{
  int wid = (blockIdx.x * blockDim.x + threadIdx.x) >> 6;
  if (wid >= npair) return;
  int lane = threadIdx.x & 63;
  int f = lane * 4;
  size_t o1 = (size_t)idx1[wid] * 256 + f;
  size_t o2 = (size_t)idx2[wid] * 256 + f;

  f4 R1 = ldb4(x1 + o1);    acc4(R1, ldb4(xfp + o2));   wave_ln(R1);
  f4 I1 = ldb4(p2 + o1);    acc4(I1, ldb4(xskip + o2)); wave_ln(I1);
  f4 R2 = ldb4(xskip + o1); acc4(R2, ldb4(p2 + o2));    wave_ln(R2);
  f4 I2 = ldb4(xfp + o1);   acc4(I2, ldb4(x1 + o2));    wave_ln(I2);

  f4 R, I;
  R.x = R1.x*R2.x - I1.x*I2.x;  I.x = R1.x*I2.x + I1.x*R2.x;
  R.y = R1.y*R2.y - I1.y*I2.y;  I.y = R1.y*I2.y + I1.y*R2.y;
  R.z = R1.z*R2.z - I1.z*I2.z;  I.z = R1.z*I2.z + I1.z*R2.z;
  R.w = R1.w*R2.w - I1.w*I2.w;  I.w = R1.w*I2.w + I1.w*R2.w;
  wave_ln(R); wave_ln(I);

  f4 wr = ld4(wR + f), wi = ld4(wI + f);
  float r_ = R.x*wr.x + I.x*wi.x + R.y*wr.y + I.y*wi.y
           + R.z*wr.z + I.z*wi.z + R.w*wr.w + I.w*wi.w;
  float i_ = I.x*wr.x - R.x*wi.x + I.y*wr.y - R.y*wi.y
           + I.z*wr.z - R.z*wi.z + I.w*wr.w - R.w*wi.w;
  float t = r_ + i_;
#pragma unroll
  for (int o = 32; o; o >>= 1) t += __shfl_xor(t, o, 64);
  if (lane == 0) out[wid] = 1.f / (1.f + expf(-t));
}

extern "C" void kernel_launch(void* const* d_in, const int* in_sizes, int n_in,
                              void* d_out, int out_size, void* d_ws, size_t ws_size,
                              hipStream_t stream) {
  (void)in_sizes; (void)n_in; (void)out_size; (void)ws_size;
  const float* seq        = (const float*)d_in[0];
  const int*   ppi        = (const int*)d_in[1];
  const int*   ddi        = (const int*)d_in[2];
  const int*   dti        = (const int*)d_in[3];
  const int*   idx1       = (const int*)d_in[4];
  const int*   idx2       = (const int*)d_in[5];
  const float* seq_init_W = (const float*)d_in[6];
  const float* gs1_gcn_W  = (const float*)d_in[7];
  const float* gs1_gcn_b  = (const float*)d_in[8];
  const float* gs1_lin_W  = (const float*)d_in[9];
  const float* gs1_ln_w   = (const float*)d_in[10];
  const float* gs1_ln_b   = (const float*)d_in[11];
  const float* gs2_gcn_W  = (const float*)d_in[12];
  const float* gs2_gcn_b  = (const float*)d_in[13];
  const float* gs2_lin_W  = (const float*)d_in[14];
  const float* gs2_ln_w   = (const float*)d_in[15];
  const float* gs2_ln_b   = (const float*)d_in[16];
  const float* drug_emb   = (const float*)d_in[17];
  const float* prot_emb   = (const float*)d_in[18];
  const float* pp1_W = (const float*)d_in[19]; const float* pp1_b = (const float*)d_in[20];
  const float* td1_W = (const float*)d_in[21]; const float* td1_b = (const float*)d_in[22];
  const float* pr1_W = (const float*)d_in[23]; const float* pr1_b = (const float*)d_in[24];
  const float* dd1_W = (const float*)d_in[25]; const float* dd1_b = (const float*)d_in[26];
  const float* dt1_W = (const float*)d_in[27]; const float* dt1_b = (const float*)d_in[28];
  const float* dr1_W = (const float*)d_in[29]; const float* dr1_b = (const float*)d_in[30];
  const float* pp2_W = (const float*)d_in[31]; const float* pp2_b = (const float*)d_in[32];
  const float* td2_W = (const float*)d_in[33]; const float* td2_b = (const float*)d_in[34];
  const float* pr2_W = (const float*)d_in[35]; const float* pr2_b = (const float*)d_in[36];
  // d_in[37..42]: dd2/dt2/dr2 — dead code in ASC path
  const float* seq_fc_W  = (const float*)d_in[43];
  const float* skip_fc_W = (const float*)d_in[44];
  const float* wR = (const float*)d_in[45];
  const float* wI = (const float*)d_in[46];
  float* outp = (float*)d_out;

  float* ws = (float*)d_ws;
  const size_t NB = (size_t)PN * 256;
  float* F0 = ws;                        // x_seq fp32 (for P6 LN)
  int*   degP = (int*)(ws + NB);
  int*   degD = degP + PN;
  int*   cntD = degD + DN;
  int*   cntP = cntD + DN;
  float* dinvP = (float*)(cntP + PN);
  float* dinvD = dinvP + PN;
  float* icD   = dinvD + DN;
  float* icP   = icD + DN;
  int* rowptrP  = (int*)(icP + PN);
  int* rowptrD  = rowptrP  + PN + 1;
  int* rowptrTD = rowptrD  + DN + 1;
  int* rowptrTP = rowptrTD + DN + 1;
  int* curP  = rowptrTP + PN + 1;
  int* curD  = curP + PN;
  int* curTD = curD + DN;
  int* curTP = curTD + DN;
  int* colP  = curTP + PN;      // EPPI
  int* colD  = colP + EPPI;     // EDDI
  int* colTD = colD + EDDI;     // EDTI
  int* colTP = colTD + EDTI;    // EDTI

  // bf16 region (aligned to 64B)
  unsigned long long waddr = (unsigned long long)(colTP + EDTI);
  waddr = (waddr + 63ULL) & ~63ULL;
  __bf16* wb = (__bf16*)waddr;
  __bf16* Wseq  = wb;                           // [256,1024]
  __bf16* pair0 = Wseq + 256*1024;              // each pair [512,256]
  __bf16* pair1 = pair0 + 512*256;
  __bf16* pair2 = pair1 + 512*256;
  __bf16* pair3 = pair2 + 512*256;
  __bf16* pair4 = pair3 + 512*256;
  __bf16* sing  = pair4 + 512*256;              // dt1, td1, td2, seq_fc, skip_fc
  __bf16* Wdt1  = sing;
  __bf16* Wtd1  = sing + 65536;
  __bf16* Wtd2  = sing + 2*65536;
  __bf16* Wsfc  = sing + 3*65536;
  __bf16* Wskp  = sing + 4*65536;
  __bf16* Eseq  = sing + 5*65536;               // [20000,1024]
  __bf16* Ed    = Eseq + (size_t)PN*SEQK;       // [20000,256]
  __bf16* Ep    = Ed + NB;
  __bf16* TL    = Ep + NB;                      // [20000,512]
  __bf16* B0    = TL + (size_t)PN*512;          // x_seq -> x_fp
  __bf16* B2    = B0 + NB;                      // h -> d -> p2
  __bf16* B3    = B2 + NB;                      // x1
  __bf16* B4    = B3 + NB;                      // proj -> fp
  __bf16* B5    = B4 + NB;                      // p -> x_skip

  const dim3 blk(256);
  const dim3 g256(313, 4);              // GEMM N=256
  const dim3 g512(313, 8);              // GEMM N=512 (TL pair)
  const dim3 rgrid((PN + 3) / 4);       // wave-per-row kernels
  const dim3 cgrid((EPPI + 255) / 256, 4);

  auto GEMM = [&](const __bf16* X, const __bf16* Wt, const float* bias,
                  float* outf, __bf16* outb, int K, int ostride, int act, dim3 grid) {
    hipLaunchKernelGGL(gemm_mfma, grid, blk, 0, stream, X, Wt, bias, outf, outb, PN, K, ostride, act);
  };
  auto STAGE = [&](const int* rpG, const int* clG, const float* dv,
                   const float* gb, const float* linb,
                   const int* rpS, const int* clS, const float* ic, const __bf16* Pt,
                   const float* lw, const float* lb, __bf16* o, int n, int act) {
    hipLaunchKernelGGL(gcn_combine, rgrid, blk, 0, stream, rpG, clG, dv, TL, 512, gb, linb,
                       TL + 256, rpS, clS, ic, Pt, lw, lb, o, n, act);
  };

  // ---- converts ----
  {
    WPack p;
    const float* srcs[16] = { seq_init_W, gs1_gcn_W, gs1_lin_W, gs2_gcn_W, gs2_lin_W,
                              dd1_W, dr1_W, pp1_W, pr1_W, pp2_W, pr2_W,
                              dt1_W, td1_W, td2_W, seq_fc_W, skip_fc_W };
    __bf16* dsts[16] = { Wseq, pair0, pair0 + 65536, pair1, pair1 + 65536,
                         pair2, pair2 + 65536, pair3, pair3 + 65536, pair4, pair4 + 65536,
                         Wdt1, Wtd1, Wtd2, Wsfc, Wskp };
    for (int i = 0; i < 16; ++i) { p.src[i] = srcs[i]; p.dst[i] = dsts[i]; p.n[i] = (i == 0) ? 256*1024 : 256*256; }
    hipLaunchKernelGGL(convert_weights, dim3(16, 16), blk, 0, stream, p);
  }
  {
    EPack p;
    p.src[0] = seq;      p.dst[0] = Eseq; p.n[0] = PN * SEQK;
    p.src[1] = drug_emb; p.dst[1] = Ed;   p.n[1] = PN * 256;
    p.src[2] = prot_emb; p.dst[2] = Ep;   p.n[2] = PN * 256;
    hipLaunchKernelGGL(convert_emb, dim3(2048, 3), blk, 0, stream, p);
  }

  // ---- degrees & CSR build ----
  hipMemsetAsync(degP, 0, 4 * sizeof(int) * PN, stream);
  {
    C4 c;
    c.idx[0] = ppi + EPPI; c.cnt[0] = degP; c.n[0] = EPPI;
    c.idx[1] = ddi + EDDI; c.cnt[1] = degD; c.n[1] = EDDI;
    c.idx[2] = dti;        c.cnt[2] = cntD; c.n[2] = EDTI;
    c.idx[3] = dti + EDTI; c.cnt[3] = cntP; c.n[3] = EDTI;
    hipLaunchKernelGGL(count4, cgrid, blk, 0, stream, c);
  }
  hipLaunchKernelGGL(finalize_deg, dim3((PN+255)/256), blk, 0, stream,
                     degP, degD, cntD, cntP, dinvP, dinvD, icD, icP, PN);
  {
    S4 s;
    s.cnt[0] = degP; s.rowptr[0] = rowptrP;  s.cur[0] = curP;  s.n[0] = PN;
    s.cnt[1] = degD; s.rowptr[1] = rowptrD;  s.cur[1] = curD;  s.n[1] = DN;
    s.cnt[2] = cntD; s.rowptr[2] = rowptrTD; s.cur[2] = curTD; s.n[2] = DN;
    s.cnt[3] = cntP; s.rowptr[3] = rowptrTP; s.cur[3] = curTP; s.n[3] = PN;
    hipLaunchKernelGGL(scan4, dim3(1, 4), dim3(1024), 0, stream, s);
  }
  {
    FI4 f;
    f.src[0] = ppi;        f.dst[0] = ppi + EPPI; f.cur[0] = curP;  f.col[0] = colP;  f.n[0] = EPPI;
    f.src[1] = ddi;        f.dst[1] = ddi + EDDI; f.cur[1] = curD;  f.col[1] = colD;  f.n[1] = EDDI;
    f.src[2] = dti + EDTI; f.dst[2] = dti;        f.cur[2] = curTD; f.col[2] = colTD; f.n[2] = EDTI;
    f.src[3] = dti;        f.dst[3] = dti + EDTI; f.cur[3] = curTP; f.col[3] = colTP; f.n[3] = EDTI;
    hipLaunchKernelGGL(fill4, cgrid, blk, 0, stream, f);
  }

  // ---- P1: x_seq = relu(Eseq @ Wseq^T) -> F0 + B0 ----
  GEMM(Eseq, Wseq, nullptr, F0, B0, SEQK, 256, 1, g256);

  // ---- P2 (gs1): h -> B2 ----
  GEMM(B0, pair0, nullptr, nullptr, TL, 256, 512, 0, g512);
  STAGE(rowptrP, colP, dinvP, gs1_gcn_b, nullptr, nullptr, nullptr, nullptr, nullptr,
        gs1_ln_w, gs1_ln_b, B2, PN, 1);

  // ---- P3 (gs2): x1 -> B3 ----
  GEMM(B2, pair1, nullptr, nullptr, TL, 256, 512, 0, g512);
  STAGE(rowptrP, colP, dinvP, gs2_gcn_b, nullptr, nullptr, nullptr, nullptr, nullptr,
        gs2_ln_w, gs2_ln_b, B3, PN, 0);

  // ---- P4d (drug layer 1): d -> B2 ----
  GEMM(Ed, pair2, nullptr, nullptr, TL, 256, 512, 0, g512);        // dd1 | dr1
  GEMM(Ep, Wdt1, dt1_b, nullptr, B4, 256, 256, 0, g256);           // proj_p
  STAGE(rowptrD, colD, dinvD, dd1_b, dr1_b, rowptrTD, colTD, icD, B4,
        nullptr, nullptr, B2, DN, 1);

  // ---- P4p (protein layer 1): p -> B5 ----
  GEMM(Ep, pair3, nullptr, nullptr, TL, 256, 512, 0, g512);        // pp1 | pr1
  GEMM(Ed, Wtd1, td1_b, nullptr, B4, 256, 256, 0, g256);           // proj_d
  STAGE(rowptrP, colP, dinvP, pp1_b, pr1_b, rowptrTP, colTP, icP, B4,
        nullptr, nullptr, B5, PN, 1);

  // ---- P5 (protein layer 2): p2 -> B2 ----
  GEMM(B2, Wtd2, td2_b, nullptr, B4, 256, 256, 0, g256);           // proj (td2) from d
  GEMM(B5, pair4, nullptr, nullptr, TL, 256, 512, 0, g512);        // pp2 | pr2 from p
  STAGE(rowptrP, colP, dinvP, pp2_b, pr2_b, rowptrTP, colTP, icP, B4,
        nullptr, nullptr, B2, PN, 0);

  // ---- P6: fuse precompute ----
  hipLaunchKernelGGL(ln_elu, rgrid, blk, 0, stream, F0, B4, PN);   // fp
  GEMM(B4, Wsfc, nullptr, nullptr, B0, 256, 256, 2, g256);         // x_fp -> B0
  GEMM(Ep, Wskp, nullptr, nullptr, B5, 256, 256, 0, g256);         // x_skip -> B5

  // ---- P7: pair epilogue ----
  hipLaunchKernelGGL(pair_kernel, dim3((NPAIRN + 3) / 4), blk, 0, stream,
                     B3, B0, B2, B5, idx1, idx2, wR, wI, outp, NPAIRN);
}